// Round 1
// baseline (6691.953 us; speedup 1.0000x reference)
//
#include <hip/hip_runtime.h>
#include <math.h>

// Problem constants (from reference)
#define SS 512
#define LL 128
#define WW 64
#define DD 768
#define HHD 8
#define TT 8192
#define EG 8192
#define NN 8705          // 1 + S + T
#define MSW 32768        // S*W
#define DKH 96           // D/H

// ---------------------------------------------------------------------------
// pos/gidx/mask from one-hot s_idx: one wave per (s,w) row of 128 floats.
__global__ __launch_bounds__(256) void k_pos(const float* __restrict__ s_idx,
                                             int* __restrict__ gidx,
                                             float* __restrict__ mask) {
  int row = blockIdx.x * 4 + (threadIdx.x >> 6);   // 0..32767
  int lane = threadIdx.x & 63;
  const float* p = s_idx + (size_t)row * LL;
  float v0 = p[lane], v1 = p[lane + 64];
  float msum = v0 + v1;
  int idx = v0 > 0.5f ? lane : (v1 > 0.5f ? lane + 64 : -1);
#pragma unroll
  for (int off = 32; off; off >>= 1) {
    msum += __shfl_xor(msum, off, 64);
    int o = __shfl_xor(idx, off, 64);
    idx = o > idx ? o : idx;
  }
  if (lane == 0) {
    int s = row >> 6;  // W=64
    gidx[row] = s * LL + (idx < 0 ? 0 : idx);
    mask[row] = msum;
  }
}

// ---------------------------------------------------------------------------
// fp32 GEMM: Cout[M,768] = act( gather(A,rowidx)[M,768] @ Wt[768,768] + bias + addC )
// 128x128 tile, BK=8, 256 threads, 8x8 microtile in 4x4 quadrants.
__global__ __launch_bounds__(256) void k_gemm(const float* __restrict__ A,
                                              const int* __restrict__ rowidx,
                                              const float* __restrict__ Wt,
                                              const float* __restrict__ bias,
                                              const float* __restrict__ addC,
                                              float* __restrict__ Cout,
                                              int M, int act) {
  __shared__ float As[8][132];
  __shared__ float Bs[8][132];
  const int tid = threadIdx.x;
  const int tx = tid & 15;        // 0..15 (cols)
  const int ty = tid >> 4;        // 0..15 (rows)
  const int bn = blockIdx.x * 128;
  const int bm = blockIdx.y * 128;
  // A tile load mapping: 2 threads per row (float4 each)
  const int lr = tid >> 1;        // 0..127
  const int lkq = tid & 1;        // 0/1 -> k offset 0/4
  long aoff = -1;
  {
    int arow = bm + lr;
    if (arow < M) aoff = (long)(rowidx ? rowidx[arow] : arow) * DD;
  }
  // B tile load mapping
  const int bkr = tid >> 5;       // 0..7
  const int bnq = tid & 31;       // 0..31

  float acc[8][8] = {};
  for (int k0 = 0; k0 < DD; k0 += 8) {
    float4 av = make_float4(0.f, 0.f, 0.f, 0.f);
    if (aoff >= 0) av = *(const float4*)(A + aoff + k0 + lkq * 4);
    As[lkq * 4 + 0][lr] = av.x;
    As[lkq * 4 + 1][lr] = av.y;
    As[lkq * 4 + 2][lr] = av.z;
    As[lkq * 4 + 3][lr] = av.w;
    *(float4*)&Bs[bkr][bnq * 4] =
        *(const float4*)(Wt + (long)(k0 + bkr) * DD + bn + bnq * 4);
    __syncthreads();
#pragma unroll
    for (int k = 0; k < 8; ++k) {
      float a[8], b[8];
      *(float4*)&a[0] = *(const float4*)&As[k][ty * 4];
      *(float4*)&a[4] = *(const float4*)&As[k][64 + ty * 4];
      *(float4*)&b[0] = *(const float4*)&Bs[k][tx * 4];
      *(float4*)&b[4] = *(const float4*)&Bs[k][64 + tx * 4];
#pragma unroll
      for (int i = 0; i < 8; ++i)
#pragma unroll
        for (int j = 0; j < 8; ++j) acc[i][j] = fmaf(a[i], b[j], acc[i][j]);
    }
    __syncthreads();
  }
#pragma unroll
  for (int i = 0; i < 8; ++i) {
    int gm = bm + (i < 4 ? ty * 4 + i : 64 + ty * 4 + (i - 4));
    if (gm >= M) continue;
#pragma unroll
    for (int jh = 0; jh < 2; ++jh) {
      int gn = bn + (jh ? 64 + tx * 4 : tx * 4);
      long ro = (long)gm * DD + gn;
      float4 v;
      float* vv = (float*)&v;
#pragma unroll
      for (int j = 0; j < 4; ++j) {
        float t = acc[i][jh * 4 + j];
        if (bias) t += bias[gn + j];
        if (addC) t += addC[ro + j];
        if (act) t = fmaxf(t, 0.f);
        vv[j] = t;
      }
      *(float4*)(Cout + ro) = v;
    }
  }
}

// ---------------------------------------------------------------------------
// Attention + exact entmax-1.5 -> latent adjacency. One block per sentence.
__global__ __launch_bounds__(256) void k_attn(const float* __restrict__ Q,
                                              const float* __restrict__ K,
                                              const float* __restrict__ mask,
                                              float* __restrict__ lat) {
  __shared__ float qt[64][97];
  __shared__ float kt[64][97];
  __shared__ float sc[64][65];
  __shared__ float mk[64];
  const int s = blockIdx.x;
  const int tid = threadIdx.x;
  const int tx = tid & 15, ty = tid >> 4;
  const int wv = tid >> 6, lane = tid & 63;
  if (tid < 64) mk[tid] = mask[s * 64 + tid];
  float regacc[16];
#pragma unroll
  for (int i = 0; i < 16; ++i) regacc[i] = 0.f;

  for (int h = 0; h < HHD; ++h) {
    __syncthreads();  // protect sc reads of prev head + mk init
    for (int i = tid; i < 64 * 96; i += 256) {
      int w = i / 96, d = i - w * 96;
      size_t go = (size_t)(s * 64 + w) * DD + h * DKH + d;
      qt[w][d] = Q[go];
      kt[w][d] = K[go];
    }
    __syncthreads();
    // scores 4x4 per thread
    float accs[4][4] = {};
    for (int d = 0; d < 96; ++d) {
      float qv[4], kv[4];
#pragma unroll
      for (int i = 0; i < 4; ++i) qv[i] = qt[ty * 4 + i][d];
#pragma unroll
      for (int j = 0; j < 4; ++j) kv[j] = kt[tx * 4 + j][d];
#pragma unroll
      for (int i = 0; i < 4; ++i)
#pragma unroll
        for (int j = 0; j < 4; ++j) accs[i][j] = fmaf(qv[i], kv[j], accs[i][j]);
    }
    const float scale = 0.10206207261596577f;  // 1/sqrt(96)
#pragma unroll
    for (int i = 0; i < 4; ++i)
#pragma unroll
      for (int j = 0; j < 4; ++j) {
        float v = accs[i][j] * scale;
        if (mk[tx * 4 + j] == 0.f) v = -1e9f;
        sc[ty * 4 + i][tx * 4 + j] = v;
      }
    __syncthreads();
    // entmax-1.5 per row; wave handles rows wv*16 .. wv*16+15, lane = column
#pragma unroll
    for (int it = 0; it < 16; ++it) {
      const int r = wv * 16 + it;
      float x = sc[r][lane] * 0.5f;
      float m = x;
#pragma unroll
      for (int off = 32; off; off >>= 1) m = fmaxf(m, __shfl_xor(m, off, 64));
      x -= m;
      // bitonic sort (descending) across 64 lanes
      float z = x;
      for (int k = 2; k <= 64; k <<= 1)
        for (int j = k >> 1; j; j >>= 1) {
          float o = __shfl_xor(z, j, 64);
          bool lower = (lane & j) == 0;
          bool takeMax = ((lane & k) == 0) ? lower : !lower;
          z = takeMax ? fmaxf(z, o) : fminf(z, o);
        }
      // inclusive prefix sums of z and z^2
      float cz = z, czz = z * z;
      for (int off = 1; off < 64; off <<= 1) {
        float t1 = __shfl_up(cz, off, 64);
        float t2 = __shfl_up(czz, off, 64);
        if (lane >= off) { cz += t1; czz += t2; }
      }
      float kk = (float)(lane + 1);
      float mean = cz / kk;
      float ss = kk * (czz / kk - mean * mean);
      float delta = (1.f - ss) / kk;
      float sq = delta > 0.f ? sqrtf(delta) : 0.f;
      float tau = mean - sq;
      unsigned long long bal = __ballot(tau <= z);
      int support = __popcll(bal);
      float tau_star = __shfl(tau, support - 1, 64);
      float p = fmaxf(x - tau_star, 0.f);
      regacc[it] += p * p;
    }
  }
#pragma unroll
  for (int it = 0; it < 16; ++it)
    lat[(size_t)s * 4096 + (wv * 16 + it) * 64 + lane] = regacc[it] * 0.125f;
}

// ---------------------------------------------------------------------------
// Batched dual adjacency propagation: Od[s]=dep[s]@Hh[s], Ol[s]=lat[s]@Hh[s]
__global__ __launch_bounds__(256) void k_dualadj(const float* __restrict__ dep,
                                                 const float* __restrict__ lat,
                                                 const float* __restrict__ Hh,
                                                 float* __restrict__ Od,
                                                 float* __restrict__ Ol) {
  __shared__ float Pd[64][68];
  __shared__ float Pl[64][68];
  __shared__ float Hc[64][68];
  const int s = blockIdx.y;
  const int c0 = blockIdx.x * 64;
  const int tid = threadIdx.x;
  const int tx = tid & 15, ty = tid >> 4;
  for (int i = tid; i < 4096; i += 256) {
    int r = i >> 6, c = i & 63;
    Pd[r][c] = dep[(size_t)s * 4096 + i];
    Pl[r][c] = lat[(size_t)s * 4096 + i];
  }
  for (int i = tid; i < 1024; i += 256) {
    int r = i >> 4, f = i & 15;
    *(float4*)&Hc[r][f * 4] =
        *(const float4*)(Hh + (size_t)(s * 64 + r) * DD + c0 + f * 4);
  }
  __syncthreads();
  float ad[4][4] = {}, al[4][4] = {};
  for (int w2 = 0; w2 < 64; ++w2) {
    float4 b4 = *(const float4*)&Hc[w2][tx * 4];
    float bb[4] = {b4.x, b4.y, b4.z, b4.w};
    float pd[4], pl[4];
#pragma unroll
    for (int i = 0; i < 4; ++i) {
      pd[i] = Pd[ty * 4 + i][w2];
      pl[i] = Pl[ty * 4 + i][w2];
    }
#pragma unroll
    for (int i = 0; i < 4; ++i)
#pragma unroll
      for (int j = 0; j < 4; ++j) {
        ad[i][j] = fmaf(pd[i], bb[j], ad[i][j]);
        al[i][j] = fmaf(pl[i], bb[j], al[i][j]);
      }
  }
#pragma unroll
  for (int i = 0; i < 4; ++i) {
    size_t ro = (size_t)(s * 64 + ty * 4 + i) * DD + c0 + tx * 4;
    float4 vd, vl;
    vd.x = ad[i][0]; vd.y = ad[i][1]; vd.z = ad[i][2]; vd.w = ad[i][3];
    vl.x = al[i][0]; vl.y = al[i][1]; vl.z = al[i][2]; vl.w = al[i][3];
    *(float4*)(Od + ro) = vd;
    *(float4*)(Ol + ro) = vl;
  }
}

// ---------------------------------------------------------------------------
// gated fusion: dst = relu(sigmoid(g1)*om + (1-sigmoid(g1))*lm + bias)
__global__ __launch_bounds__(256) void k_gate(const float* __restrict__ g1,
                                              const float* __restrict__ om,
                                              const float* __restrict__ lm,
                                              const float* __restrict__ bias,
                                              float* __restrict__ dst) {
  size_t i = (size_t)blockIdx.x * 256 + threadIdx.x;
  float g = 1.f / (1.f + expf(-g1[i]));
  float v = g * om[i] + (1.f - g) * lm[i];
  v += bias[i % DD];
  dst[i] = fmaxf(v, 0.f);
}

// residual: X[row,:] += sent_embed[gidx[row],:]  (float4 granularity)
__global__ __launch_bounds__(256) void k_resadd(float* __restrict__ X,
                                                const float* __restrict__ SE,
                                                const int* __restrict__ gidx) {
  size_t i = (size_t)blockIdx.x * 256 + threadIdx.x;  // float4 units
  size_t row = i / 192, q = i % 192;
  float4 a = ((float4*)X)[i];
  float4 b = ((const float4*)SE)[(size_t)gidx[row] * 192 + q];
  a.x += b.x; a.y += b.y; a.z += b.z; a.w += b.w;
  ((float4*)X)[i] = a;
}

// node feature assembly [NN,768]
__global__ __launch_bounds__(256) void k_feats(const float* __restrict__ doc,
                                               const float* __restrict__ scls,
                                               const int* __restrict__ t_sid,
                                               const int* __restrict__ t_index,
                                               const float* __restrict__ X,
                                               float* __restrict__ F) {
  size_t i = (size_t)blockIdx.x * 256 + threadIdx.x;
  if (i >= (size_t)NN * 192) return;
  size_t n = i / 192, q = i % 192;
  float4 v;
  if (n == 0) v = ((const float4*)doc)[q];
  else if (n <= SS) v = ((const float4*)scls)[(n - 1) * 192 + q];
  else {
    size_t t = n - 1 - SS;
    size_t row = (size_t)t_sid[t] * WW + t_index[t];
    v = ((const float4*)X)[row * 192 + q];
  }
  ((float4*)F)[i] = v;
}

__global__ __launch_bounds__(256) void k_deg(const int* __restrict__ dst,
                                             float* __restrict__ deg) {
  int e = blockIdx.x * 256 + threadIdx.x;
  atomicAdd(&deg[dst[e]], 1.f);
}

__global__ __launch_bounds__(256) void k_scatter(const int* __restrict__ dst,
                                                 const float* __restrict__ msg,
                                                 float* __restrict__ agg) {
  size_t i = (size_t)blockIdx.x * 256 + threadIdx.x;
  int e = (int)(i / DD), d = (int)(i % DD);
  atomicAdd(&agg[(size_t)dst[e] * DD + d], msg[i]);
}

__global__ __launch_bounds__(256) void k_accum(const float* __restrict__ agg,
                                               const float* __restrict__ deg,
                                               float* __restrict__ hsum) {
  size_t i = (size_t)blockIdx.x * 256 + threadIdx.x;  // float4 units
  if (i >= (size_t)NN * 192) return;
  size_t n = i / 192;
  float r = 1.f / fmaxf(deg[n], 1.f);
  float4 a = ((const float4*)agg)[i];
  float4 h = ((float4*)hsum)[i];
  h.x = fmaf(a.x, r, h.x); h.y = fmaf(a.y, r, h.y);
  h.z = fmaf(a.z, r, h.z); h.w = fmaf(a.w, r, h.w);
  ((float4*)hsum)[i] = h;
}

// final predictor: out[n,:5] = [F|h1|h2][n,:] @ pw + pb ; one block per node
__global__ __launch_bounds__(256) void k_pred(const float* __restrict__ F,
                                              const float* __restrict__ h1,
                                              const float* __restrict__ h2,
                                              const float* __restrict__ pw,
                                              const float* __restrict__ pb,
                                              float* __restrict__ out) {
  const int n = blockIdx.x;
  const int tid = threadIdx.x;
  float acc[5] = {};
  for (int k = tid; k < 3 * DD; k += 256) {
    float v;
    if (k < DD) v = F[(size_t)n * DD + k];
    else if (k < 2 * DD) v = h1[(size_t)n * DD + k - DD];
    else v = h2[(size_t)n * DD + k - 2 * DD];
    const float* w = pw + (size_t)k * 5;
#pragma unroll
    for (int o = 0; o < 5; ++o) acc[o] = fmaf(v, w[o], acc[o]);
  }
#pragma unroll
  for (int o = 0; o < 5; ++o)
    for (int off = 32; off; off >>= 1) acc[o] += __shfl_xor(acc[o], off, 64);
  __shared__ float red[5][4];
  const int wv = tid >> 6, lane = tid & 63;
  if (lane == 0)
#pragma unroll
    for (int o = 0; o < 5; ++o) red[o][wv] = acc[o];
  __syncthreads();
  if (tid == 0)
#pragma unroll
    for (int o = 0; o < 5; ++o)
      out[(size_t)n * 5 + o] = red[o][0] + red[o][1] + red[o][2] + red[o][3] + pb[o];
}

// ---------------------------------------------------------------------------
extern "C" void kernel_launch(void* const* d_in, const int* in_sizes, int n_in,
                              void* d_out, int out_size, void* d_ws, size_t ws_size,
                              hipStream_t stream) {
  const float* sent_embed = (const float*)d_in[0];
  const float* s_idx      = (const float*)d_in[1];
  const float* dep_adj    = (const float*)d_in[2];
  const float* doc_cls    = (const float*)d_in[3];
  const float* sent_cls   = (const float*)d_in[4];
  const int*   t_sid      = (const int*)d_in[5];
  const int*   t_index    = (const int*)d_in[6];
  const int*   e_src      = (const int*)d_in[7];
  const int*   e_dst      = (const int*)d_in[8];
  const float* wq_w = (const float*)d_in[9];
  const float* wq_b = (const float*)d_in[10];
  const float* wk_w = (const float*)d_in[11];
  const float* wk_b = (const float*)d_in[12];
  const float* gc1_w   = (const float*)d_in[13];
  const float* gc1_b   = (const float*)d_in[14];
  const float* gc1_l1w = (const float*)d_in[15];
  const float* gc1_l1b = (const float*)d_in[16];
  const float* gc1_l2w = (const float*)d_in[17];
  const float* gc1_l2b = (const float*)d_in[18];
  const float* gc2_w   = (const float*)d_in[19];
  const float* gc2_b   = (const float*)d_in[20];
  const float* gc2_l1w = (const float*)d_in[21];
  const float* gc2_l1b = (const float*)d_in[22];
  const float* gc2_l2w = (const float*)d_in[23];
  const float* gc2_l2b = (const float*)d_in[24];
  const float* rel1_w    = (const float*)d_in[25];
  const float* rel1_loop = (const float*)d_in[26];
  const float* rel1_b    = (const float*)d_in[27];
  const float* rel2_w    = (const float*)d_in[28];
  const float* rel2_loop = (const float*)d_in[29];
  const float* rel2_b    = (const float*)d_in[30];
  const float* pred_w = (const float*)d_in[31];
  const float* pred_b = (const float*)d_in[32];
  float* out = (float*)d_out;

  // workspace carve (floats). Total ~311 MB.
  const size_t BUF = (size_t)MSW * DD;     // 25,165,824
  const size_t NODE = (size_t)NN * DD;     // 6,685,440
  float* WSA = (float*)d_ws;
  float* WSB = WSA + BUF;
  float* WSC = WSB + BUF;
  float* LATJ = WSC + BUF;                 // S*W*W = 2,097,152
  int*   GIDX = (int*)(LATJ + (size_t)SS * WW * WW);
  float* MASK = (float*)(GIDX + MSW);
  // graph-phase aliases (live after GC phase frees A/B/C)
  float* Ffeat = WSB;
  float* H1 = WSB + NODE;
  float* H2 = WSB + 2 * NODE;
  float* AGG = WSA;
  float* DEG = WSA + NODE;
  float* MSG = WSA + 7000000;              // past AGG+DEG, 16B-aligned
  float* HSUM = WSC;

  dim3 blk(256);
  dim3 gemmG(6, MSW / 128);        // 6 x 256
  dim3 gemmE(6, EG / 128);         // 6 x 64
  dim3 gemmN(6, (NN + 127) / 128); // 6 x 69

  // 1) word positions / mask
  k_pos<<<MSW / 4, blk, 0, stream>>>(s_idx, GIDX, MASK);
  // 2) Q,K projections (gathered word embeddings)
  k_gemm<<<gemmG, blk, 0, stream>>>(sent_embed, GIDX, wq_w, wq_b, nullptr, WSA, MSW, 0);
  k_gemm<<<gemmG, blk, 0, stream>>>(sent_embed, GIDX, wk_w, wk_b, nullptr, WSB, MSW, 0);
  // 3) entmax attention -> latent adjacency
  k_attn<<<SS, blk, 0, stream>>>(WSA, WSB, MASK, LATJ);
  // 4) gated GCN layer 1 (x = word_embed via gather)
  k_gemm<<<gemmG, blk, 0, stream>>>(sent_embed, GIDX, gc1_w, nullptr, nullptr, WSC, MSW, 0);
  k_dualadj<<<dim3(12, SS), blk, 0, stream>>>(dep_adj, LATJ, WSC, WSA, WSB);
  k_gemm<<<gemmG, blk, 0, stream>>>(WSA, nullptr, gc1_l1w, gc1_l1b, nullptr, WSC, MSW, 0);
  k_gemm<<<gemmG, blk, 0, stream>>>(WSB, nullptr, gc1_l2w, gc1_l2b, WSC, WSC, MSW, 0);
  k_gate<<<(MSW * DD) / 256, blk, 0, stream>>>(WSC, WSA, WSB, gc1_b, WSA);  // x1 = A
  // 5) gated GCN layer 2
  k_gemm<<<gemmG, blk, 0, stream>>>(WSA, nullptr, gc2_w, nullptr, nullptr, WSB, MSW, 0);
  k_dualadj<<<dim3(12, SS), blk, 0, stream>>>(dep_adj, LATJ, WSB, WSC, WSA);
  k_gemm<<<gemmG, blk, 0, stream>>>(WSC, nullptr, gc2_l1w, gc2_l1b, nullptr, WSB, MSW, 0);
  k_gemm<<<gemmG, blk, 0, stream>>>(WSA, nullptr, gc2_l2w, gc2_l2b, WSB, WSB, MSW, 0);
  k_gate<<<(MSW * DD) / 256, blk, 0, stream>>>(WSB, WSC, WSA, gc2_b, WSC);  // x2 = C
  k_resadd<<<(MSW * 192) / 256, blk, 0, stream>>>(WSC, sent_embed, GIDX);   // x_final = C
  // 6) node features
  k_feats<<<((size_t)NN * 192 + 255) / 256, blk, 0, stream>>>(
      doc_cls, sent_cls, t_sid, t_index, WSC, Ffeat);
  // 7) two relational GCN layers
  const float* relw[2]  = {rel1_w, rel2_w};
  const float* rellp[2] = {rel1_loop, rel2_loop};
  const float* relb[2]  = {rel1_b, rel2_b};
  const float* rin[2]   = {Ffeat, H1};
  float* rout[2]        = {H1, H2};
  for (int l = 0; l < 2; ++l) {
    hipMemsetAsync(HSUM, 0, NODE * sizeof(float), stream);
    for (int r = 0; r < 4; ++r) {
      hipMemsetAsync(AGG, 0, NODE * sizeof(float), stream);
      hipMemsetAsync(DEG, 0, NN * sizeof(float), stream);
      k_gemm<<<gemmE, blk, 0, stream>>>(rin[l], e_src + r * EG,
                                        relw[l] + (size_t)r * DD * DD,
                                        nullptr, nullptr, MSG, EG, 0);
      k_deg<<<EG / 256, blk, 0, stream>>>(e_dst + r * EG, DEG);
      k_scatter<<<((size_t)EG * DD) / 256, blk, 0, stream>>>(e_dst + r * EG, MSG, AGG);
      k_accum<<<((size_t)NN * 192 + 255) / 256, blk, 0, stream>>>(AGG, DEG, HSUM);
    }
    k_gemm<<<gemmN, blk, 0, stream>>>(rin[l], nullptr, rellp[l], relb[l], HSUM,
                                      rout[l], NN, 1);
  }
  // 8) predictor
  k_pred<<<NN, blk, 0, stream>>>(Ffeat, H1, H2, pred_w, pred_b, out);
}

// Round 2
// 2495.104 us; speedup vs baseline: 2.6820x; 2.6820x over previous
//
#include <hip/hip_runtime.h>
#include <math.h>

// Problem constants
#define SS 512
#define LL 128
#define WW 64
#define DD 768
#define HHD 8
#define EG 8192
#define NN 8705          // 1 + S + T
#define MSW 32768        // S*W
#define DKH 96           // D/H
#define NODE_F 6685440   // NN*DD

typedef __attribute__((ext_vector_type(8))) short bf16x8;
typedef __attribute__((ext_vector_type(4))) float f32x4;

__device__ __forceinline__ ushort f2bf(float f) {
  union { float f; unsigned u; } v; v.f = f;
  unsigned r = (v.u + 0x7FFF + ((v.u >> 16) & 1)) >> 16;
  return (ushort)r;
}
__device__ __forceinline__ float bf2f(ushort b) {
  union { unsigned u; float f; } v; v.u = ((unsigned)b) << 16;
  return v.f;
}
__device__ __forceinline__ void gload16(const void* g, void* l) {
  __builtin_amdgcn_global_load_lds(
      (const __attribute__((address_space(1))) void*)g,
      (__attribute__((address_space(3))) void*)l, 16, 0, 0);
}

// ---------------------------------------------------------------------------
// pos/gidx/mask from one-hot s_idx
__global__ __launch_bounds__(256) void k_pos(const float* __restrict__ s_idx,
                                             int* __restrict__ gidx,
                                             float* __restrict__ mask) {
  int row = blockIdx.x * 4 + (threadIdx.x >> 6);
  int lane = threadIdx.x & 63;
  const float* p = s_idx + (size_t)row * LL;
  float v0 = p[lane], v1 = p[lane + 64];
  float msum = v0 + v1;
  int idx = v0 > 0.5f ? lane : (v1 > 0.5f ? lane + 64 : -1);
#pragma unroll
  for (int off = 32; off; off >>= 1) {
    msum += __shfl_xor(msum, off, 64);
    int o = __shfl_xor(idx, off, 64);
    idx = o > idx ? o : idx;
  }
  if (lane == 0) {
    int s = row >> 6;
    gidx[row] = s * LL + (idx < 0 ? 0 : idx);
    mask[row] = msum;
  }
}

// weight fp32 [768][768] -> bf16 transposed [N][K]
__global__ __launch_bounds__(256) void k_wt(const float* __restrict__ src,
                                            ushort* __restrict__ dst) {
  __shared__ float t[32][33];
  int bx = blockIdx.x % 24, by = blockIdx.x / 24;
  int r0 = by * 32, c0 = bx * 32;
  int lx = threadIdx.x & 31, ly = threadIdx.x >> 5;
#pragma unroll
  for (int i = 0; i < 4; ++i)
    t[ly + i * 8][lx] = src[(size_t)(r0 + ly + i * 8) * DD + c0 + lx];
  __syncthreads();
#pragma unroll
  for (int i = 0; i < 4; ++i)
    dst[(size_t)(c0 + ly + i * 8) * DD + r0 + lx] = f2bf(t[lx][ly + i * 8]);
}

// gather word embeddings -> bf16 [MSW,768]
__global__ __launch_bounds__(256) void k_gather(const float* __restrict__ SE,
                                                const int* __restrict__ gidx,
                                                ushort* __restrict__ WE) {
  size_t i = (size_t)blockIdx.x * 256 + threadIdx.x;  // float4 units
  size_t row = i / 192, q = i % 192;
  float4 v = ((const float4*)(SE + (size_t)gidx[row] * DD))[q];
  ushort4 o;
  o.x = f2bf(v.x); o.y = f2bf(v.y); o.z = f2bf(v.z); o.w = f2bf(v.w);
  ((ushort4*)WE)[i] = o;
}

// ---------------------------------------------------------------------------
// bf16 MFMA GEMM: C[M,768] = act( gatherA[M,768](bf16) @ BT[768,768]^T + bias + addC )
// 128x128 tile, BK=64, 16x16x32 MFMA, global_load_lds staging w/ XOR swizzle.
__global__ __launch_bounds__(256) void k_mgemm(const ushort* __restrict__ A,
                                               const int* __restrict__ rowidx,
                                               const ushort* __restrict__ BT,
                                               const float* __restrict__ bias,
                                               const float* __restrict__ addC,
                                               float* __restrict__ Cf,
                                               ushort* __restrict__ Cb,
                                               int M, int relu) {
  __shared__ ushort As[128 * 64];
  __shared__ ushort Bs[128 * 64];
  const int tid = threadIdx.x;
  const int wave = tid >> 6, lane = tid & 63;
  const int bm = blockIdx.y * 128, bn = blockIdx.x * 128;
  const int lrow = lane & 15, quad = lane >> 4;

  // staging addresses: 4 chunks each of A/B per thread per slab
  const ushort* gA[4];
  const ushort* gB[4];
#pragma unroll
  for (int j = 0; j < 4; ++j) {
    int c = (wave * 4 + j) * 64 + lane;
    int row = c >> 3, kslot = c & 7;
    int kb = kslot ^ (row & 7);
    int ar = bm + row; ar = ar < M ? ar : M - 1;
    int agr = rowidx ? rowidx[ar] : ar;
    gA[j] = A + (size_t)agr * DD + kb * 8;
    gB[j] = BT + (size_t)(bn + row) * DD + kb * 8;
  }

  f32x4 acc[4][4];
#pragma unroll
  for (int i = 0; i < 4; ++i)
#pragma unroll
    for (int j = 0; j < 4; ++j) acc[i][j] = (f32x4){0.f, 0.f, 0.f, 0.f};

  const int wm = (wave >> 1) * 64, wn = (wave & 1) * 64;

  for (int kt = 0; kt < 12; ++kt) {
#pragma unroll
    for (int j = 0; j < 4; ++j) {
      gload16(gA[j], &As[(wave * 4 + j) * 512]);
      gload16(gB[j], &Bs[(wave * 4 + j) * 512]);
      gA[j] += 64;
      gB[j] += 64;
    }
    __syncthreads();
#pragma unroll
    for (int ks = 0; ks < 2; ++ks) {
      bf16x8 af[4], bfr[4];
#pragma unroll
      for (int mi = 0; mi < 4; ++mi) {
        int r = wm + mi * 16 + lrow;
        int kc = ks * 4 + quad;
        af[mi] = *(const bf16x8*)&As[r * 64 + ((kc ^ (r & 7)) * 8)];
      }
#pragma unroll
      for (int ni = 0; ni < 4; ++ni) {
        int r = wn + ni * 16 + lrow;
        int kc = ks * 4 + quad;
        bfr[ni] = *(const bf16x8*)&Bs[r * 64 + ((kc ^ (r & 7)) * 8)];
      }
#pragma unroll
      for (int mi = 0; mi < 4; ++mi)
#pragma unroll
        for (int ni = 0; ni < 4; ++ni)
          acc[mi][ni] = __builtin_amdgcn_mfma_f32_16x16x32_bf16(
              af[mi], bfr[ni], acc[mi][ni], 0, 0, 0);
    }
    __syncthreads();
  }

#pragma unroll
  for (int mi = 0; mi < 4; ++mi) {
#pragma unroll
    for (int ni = 0; ni < 4; ++ni) {
      f32x4 v = acc[mi][ni];
      int col = bn + wn + ni * 16 + lrow;
      float bv = bias ? bias[col] : 0.f;
#pragma unroll
      for (int r = 0; r < 4; ++r) {
        int grow = bm + wm + mi * 16 + quad * 4 + r;
        if (grow >= M) continue;
        size_t off = (size_t)grow * DD + col;
        float t = v[r] + bv;
        if (addC) t += addC[off];
        if (relu) t = fmaxf(t, 0.f);
        if (Cb) Cb[off] = f2bf(t);
        else Cf[off] = t;
      }
    }
  }
}

// ---------------------------------------------------------------------------
// Attention + exact entmax-1.5 -> latent adjacency. One block per sentence.
__global__ __launch_bounds__(256) void k_attn(const float* __restrict__ Q,
                                              const float* __restrict__ K,
                                              const float* __restrict__ mask,
                                              float* __restrict__ lat) {
  __shared__ float qt[64][97];
  __shared__ float kt[64][97];
  __shared__ float sc[64][65];
  __shared__ float mk[64];
  const int s = blockIdx.x;
  const int tid = threadIdx.x;
  const int tx = tid & 15, ty = tid >> 4;
  const int wv = tid >> 6, lane = tid & 63;
  if (tid < 64) mk[tid] = mask[s * 64 + tid];
  float regacc[16];
#pragma unroll
  for (int i = 0; i < 16; ++i) regacc[i] = 0.f;

  for (int h = 0; h < HHD; ++h) {
    __syncthreads();
    for (int i = tid; i < 64 * 96; i += 256) {
      int w = i / 96, d = i - w * 96;
      size_t go = (size_t)(s * 64 + w) * DD + h * DKH + d;
      qt[w][d] = Q[go];
      kt[w][d] = K[go];
    }
    __syncthreads();
    float accs[4][4] = {};
    for (int d = 0; d < 96; ++d) {
      float qv[4], kv[4];
#pragma unroll
      for (int i = 0; i < 4; ++i) qv[i] = qt[ty * 4 + i][d];
#pragma unroll
      for (int j = 0; j < 4; ++j) kv[j] = kt[tx * 4 + j][d];
#pragma unroll
      for (int i = 0; i < 4; ++i)
#pragma unroll
        for (int j = 0; j < 4; ++j) accs[i][j] = fmaf(qv[i], kv[j], accs[i][j]);
    }
    const float scale = 0.10206207261596577f;  // 1/sqrt(96)
#pragma unroll
    for (int i = 0; i < 4; ++i)
#pragma unroll
      for (int j = 0; j < 4; ++j) {
        float v = accs[i][j] * scale;
        if (mk[tx * 4 + j] == 0.f) v = -1e9f;
        sc[ty * 4 + i][tx * 4 + j] = v;
      }
    __syncthreads();
#pragma unroll
    for (int it = 0; it < 16; ++it) {
      const int r = wv * 16 + it;
      float x = sc[r][lane] * 0.5f;
      float m = x;
#pragma unroll
      for (int off = 32; off; off >>= 1) m = fmaxf(m, __shfl_xor(m, off, 64));
      x -= m;
      float z = x;
      for (int k = 2; k <= 64; k <<= 1)
        for (int j = k >> 1; j; j >>= 1) {
          float o = __shfl_xor(z, j, 64);
          bool lower = (lane & j) == 0;
          bool takeMax = ((lane & k) == 0) ? lower : !lower;
          z = takeMax ? fmaxf(z, o) : fminf(z, o);
        }
      float cz = z, czz = z * z;
      for (int off = 1; off < 64; off <<= 1) {
        float t1 = __shfl_up(cz, off, 64);
        float t2 = __shfl_up(czz, off, 64);
        if (lane >= off) { cz += t1; czz += t2; }
      }
      float kk = (float)(lane + 1);
      float mean = cz / kk;
      float ss = kk * (czz / kk - mean * mean);
      float delta = (1.f - ss) / kk;
      float sq = delta > 0.f ? sqrtf(delta) : 0.f;
      float tau = mean - sq;
      unsigned long long bal = __ballot(tau <= z);
      int support = __popcll(bal);
      float tau_star = __shfl(tau, support - 1, 64);
      float p = fmaxf(x - tau_star, 0.f);
      regacc[it] += p * p;
    }
  }
#pragma unroll
  for (int it = 0; it < 16; ++it)
    lat[(size_t)s * 4096 + (wv * 16 + it) * 64 + lane] = regacc[it] * 0.125f;
}

// ---------------------------------------------------------------------------
// Od[s]=dep[s]@Hh[s], Ol[s]=lat[s]@Hh[s]; fp32 math, bf16 outputs
__global__ __launch_bounds__(256) void k_dualadj(const float* __restrict__ dep,
                                                 const float* __restrict__ lat,
                                                 const float* __restrict__ Hh,
                                                 ushort* __restrict__ Od,
                                                 ushort* __restrict__ Ol) {
  __shared__ float Pd[64][68];
  __shared__ float Pl[64][68];
  __shared__ float Hc[64][68];
  const int s = blockIdx.y;
  const int c0 = blockIdx.x * 64;
  const int tid = threadIdx.x;
  const int tx = tid & 15, ty = tid >> 4;
  for (int i = tid; i < 4096; i += 256) {
    int r = i >> 6, c = i & 63;
    Pd[r][c] = dep[(size_t)s * 4096 + i];
    Pl[r][c] = lat[(size_t)s * 4096 + i];
  }
  for (int i = tid; i < 1024; i += 256) {
    int r = i >> 4, f = i & 15;
    *(float4*)&Hc[r][f * 4] =
        *(const float4*)(Hh + (size_t)(s * 64 + r) * DD + c0 + f * 4);
  }
  __syncthreads();
  float ad[4][4] = {}, al[4][4] = {};
  for (int w2 = 0; w2 < 64; ++w2) {
    float4 b4 = *(const float4*)&Hc[w2][tx * 4];
    float bb[4] = {b4.x, b4.y, b4.z, b4.w};
    float pd[4], pl[4];
#pragma unroll
    for (int i = 0; i < 4; ++i) {
      pd[i] = Pd[ty * 4 + i][w2];
      pl[i] = Pl[ty * 4 + i][w2];
    }
#pragma unroll
    for (int i = 0; i < 4; ++i)
#pragma unroll
      for (int j = 0; j < 4; ++j) {
        ad[i][j] = fmaf(pd[i], bb[j], ad[i][j]);
        al[i][j] = fmaf(pl[i], bb[j], al[i][j]);
      }
  }
#pragma unroll
  for (int i = 0; i < 4; ++i) {
    size_t ro = (size_t)(s * 64 + ty * 4 + i) * DD + c0 + tx * 4;
    ushort4 vd, vl;
    vd.x = f2bf(ad[i][0]); vd.y = f2bf(ad[i][1]);
    vd.z = f2bf(ad[i][2]); vd.w = f2bf(ad[i][3]);
    vl.x = f2bf(al[i][0]); vl.y = f2bf(al[i][1]);
    vl.z = f2bf(al[i][2]); vl.w = f2bf(al[i][3]);
    *(ushort4*)&Od[ro] = vd;
    *(ushort4*)&Ol[ro] = vl;
  }
}

// gated fusion: x = relu(sigmoid(g1)*om + (1-sigmoid(g1))*lm + bias) -> bf16
__global__ __launch_bounds__(256) void k_gate(const float* __restrict__ g1,
                                              const ushort* __restrict__ om,
                                              const ushort* __restrict__ lm,
                                              const float* __restrict__ bias,
                                              ushort* __restrict__ dst) {
  size_t i = (size_t)blockIdx.x * 256 + threadIdx.x;  // 4-elem units
  float4 g4 = ((const float4*)g1)[i];
  ushort4 o4 = ((const ushort4*)om)[i];
  ushort4 l4 = ((const ushort4*)lm)[i];
  int col = (int)((i * 4) % DD);
  float gv[4] = {g4.x, g4.y, g4.z, g4.w};
  float ov[4] = {bf2f(o4.x), bf2f(o4.y), bf2f(o4.z), bf2f(o4.w)};
  float lv[4] = {bf2f(l4.x), bf2f(l4.y), bf2f(l4.z), bf2f(l4.w)};
  ushort4 r;
  ushort* rr = (ushort*)&r;
#pragma unroll
  for (int j = 0; j < 4; ++j) {
    float g = 1.f / (1.f + expf(-gv[j]));
    float v = g * ov[j] + (1.f - g) * lv[j] + bias[col + j];
    rr[j] = f2bf(fmaxf(v, 0.f));
  }
  ((ushort4*)dst)[i] = r;
}

// residual: Xbf[row,:] += sent_embed[gidx[row],:]
__global__ __launch_bounds__(256) void k_resadd(ushort* __restrict__ X,
                                                const float* __restrict__ SE,
                                                const int* __restrict__ gidx) {
  size_t i = (size_t)blockIdx.x * 256 + threadIdx.x;  // 4-elem units
  size_t row = i / 192, q = i % 192;
  ushort4 a = ((ushort4*)X)[i];
  float4 b = ((const float4*)(SE + (size_t)gidx[row] * DD))[q];
  ushort4 r;
  r.x = f2bf(bf2f(a.x) + b.x);
  r.y = f2bf(bf2f(a.y) + b.y);
  r.z = f2bf(bf2f(a.z) + b.z);
  r.w = f2bf(bf2f(a.w) + b.w);
  ((ushort4*)X)[i] = r;
}

// node feature assembly -> bf16 [NN,768]
__global__ __launch_bounds__(256) void k_feats(const float* __restrict__ doc,
                                               const float* __restrict__ scls,
                                               const int* __restrict__ t_sid,
                                               const int* __restrict__ t_index,
                                               const ushort* __restrict__ X,
                                               ushort* __restrict__ F) {
  size_t i = (size_t)blockIdx.x * 256 + threadIdx.x;  // 4-elem units
  if (i >= (size_t)NN * 192) return;
  size_t n = i / 192, q = i % 192;
  ushort4 o;
  if (n <= SS) {
    float4 v = (n == 0) ? ((const float4*)doc)[q]
                        : ((const float4*)scls)[(n - 1) * 192 + q];
    o.x = f2bf(v.x); o.y = f2bf(v.y); o.z = f2bf(v.z); o.w = f2bf(v.w);
  } else {
    size_t t = n - 1 - SS;
    size_t row = (size_t)t_sid[t] * WW + t_index[t];
    o = ((const ushort4*)X)[row * 192 + q];
  }
  ((ushort4*)F)[i] = o;
}

__global__ __launch_bounds__(256) void k_deg(const int* __restrict__ dst,
                                             float* __restrict__ deg) {
  int e = blockIdx.x * 256 + threadIdx.x;
  atomicAdd(&deg[dst[e]], 1.f);
}

__global__ __launch_bounds__(256) void k_scatter(const int* __restrict__ dst,
                                                 const float* __restrict__ msg,
                                                 float* __restrict__ agg) {
  size_t i = (size_t)blockIdx.x * 256 + threadIdx.x;
  int e = (int)(i / DD), d = (int)(i % DD);
  atomicAdd(&agg[(size_t)dst[e] * DD + d], msg[i]);
}

__global__ __launch_bounds__(256) void k_accum(const float* __restrict__ agg,
                                               const float* __restrict__ deg,
                                               float* __restrict__ hsum) {
  size_t i = (size_t)blockIdx.x * 256 + threadIdx.x;  // float4 units
  if (i >= (size_t)NN * 192) return;
  size_t n = i / 192;
  float r = 1.f / fmaxf(deg[n], 1.f);
  float4 a = ((const float4*)agg)[i];
  float4 h = ((float4*)hsum)[i];
  h.x = fmaf(a.x, r, h.x); h.y = fmaf(a.y, r, h.y);
  h.z = fmaf(a.z, r, h.z); h.w = fmaf(a.w, r, h.w);
  ((float4*)hsum)[i] = h;
}

// final predictor from bf16 bank
__global__ __launch_bounds__(256) void k_pred(const ushort* __restrict__ F,
                                              const ushort* __restrict__ h1,
                                              const ushort* __restrict__ h2,
                                              const float* __restrict__ pw,
                                              const float* __restrict__ pb,
                                              float* __restrict__ out) {
  const int n = blockIdx.x;
  const int tid = threadIdx.x;
  float acc[5] = {};
  for (int k = tid; k < 3 * DD; k += 256) {
    float v;
    if (k < DD) v = bf2f(F[(size_t)n * DD + k]);
    else if (k < 2 * DD) v = bf2f(h1[(size_t)n * DD + k - DD]);
    else v = bf2f(h2[(size_t)n * DD + k - 2 * DD]);
    const float* w = pw + (size_t)k * 5;
#pragma unroll
    for (int o = 0; o < 5; ++o) acc[o] = fmaf(v, w[o], acc[o]);
  }
#pragma unroll
  for (int o = 0; o < 5; ++o)
    for (int off = 32; off; off >>= 1) acc[o] += __shfl_xor(acc[o], off, 64);
  __shared__ float red[5][4];
  const int wv = tid >> 6, lane = tid & 63;
  if (lane == 0)
#pragma unroll
    for (int o = 0; o < 5; ++o) red[o][wv] = acc[o];
  __syncthreads();
  if (tid == 0)
#pragma unroll
    for (int o = 0; o < 5; ++o)
      out[(size_t)n * 5 + o] = red[o][0] + red[o][1] + red[o][2] + red[o][3] + pb[o];
}

// ---------------------------------------------------------------------------
extern "C" void kernel_launch(void* const* d_in, const int* in_sizes, int n_in,
                              void* d_out, int out_size, void* d_ws, size_t ws_size,
                              hipStream_t stream) {
  const float* sent_embed = (const float*)d_in[0];
  const float* s_idx      = (const float*)d_in[1];
  const float* dep_adj    = (const float*)d_in[2];
  const float* doc_cls    = (const float*)d_in[3];
  const float* sent_cls   = (const float*)d_in[4];
  const int*   t_sid      = (const int*)d_in[5];
  const int*   t_index    = (const int*)d_in[6];
  const int*   e_src      = (const int*)d_in[7];
  const int*   e_dst      = (const int*)d_in[8];
  const float* wsrc[18] = {
      (const float*)d_in[9],  (const float*)d_in[11],                    // wq, wk
      (const float*)d_in[13], (const float*)d_in[15], (const float*)d_in[17],  // gc1 w,l1w,l2w
      (const float*)d_in[19], (const float*)d_in[21], (const float*)d_in[23],  // gc2 w,l1w,l2w
      (const float*)d_in[25], (const float*)d_in[25] + 589824,
      (const float*)d_in[25] + 2 * 589824, (const float*)d_in[25] + 3 * 589824,  // rel1_w
      (const float*)d_in[26],                                            // rel1_loop
      (const float*)d_in[28], (const float*)d_in[28] + 589824,
      (const float*)d_in[28] + 2 * 589824, (const float*)d_in[28] + 3 * 589824,  // rel2_w
      (const float*)d_in[29]};                                           // rel2_loop
  const float* wq_b = (const float*)d_in[10];
  const float* wk_b = (const float*)d_in[12];
  const float* gc1_b   = (const float*)d_in[14];
  const float* gc1_l1b = (const float*)d_in[16];
  const float* gc1_l2b = (const float*)d_in[18];
  const float* gc2_b   = (const float*)d_in[20];
  const float* gc2_l1b = (const float*)d_in[22];
  const float* gc2_l2b = (const float*)d_in[24];
  const float* rel1_b = (const float*)d_in[27];
  const float* rel2_b = (const float*)d_in[30];
  const float* pred_w = (const float*)d_in[31];
  const float* pred_b = (const float*)d_in[32];
  float* out = (float*)d_out;

  // workspace carve (float offsets), total 70,385,664 floats ~= 281.5 MB
  float* WSA  = (float*)d_ws;                    // 25165824 f
  float* WSB  = WSA + 25165824;                  // 25165824 f
  float* LATJ = WSA + 50331648;                  // 2097152 f
  int*   GIDX = (int*)(WSA + 52428800);          // 32768
  float* MASK = WSA + 52461568;                  // 32768
  ushort* WEbf = (ushort*)(WSA + 52494336);      // 25165824 bf16
  ushort* WBF  = (ushort*)(WSA + 65077248);      // 18*589824 bf16
  // aliases
  ushort* OdBF = (ushort*)WSB;
  ushort* OlBF = OdBF + 25165824;
  ushort* FfeatBF = (ushort*)WSB;
  ushort* H1BF = FfeatBF + NODE_F;
  ushort* H2BF = FfeatBF + 2 * NODE_F;
  float* AGG  = WSA;
  float* DEG  = WSA + NODE_F;
  float* MSG  = WSA + 7000000;
  float* HSUM = WSA + 14000000;

  dim3 blk(256);
  dim3 gG(6, 256);   // M=32768
  dim3 gE(6, 64);    // M=8192
  dim3 gN(6, 69);    // M=8705

  // 0) weight transpose+convert, positions, gather
  for (int w = 0; w < 18; ++w)
    k_wt<<<576, blk, 0, stream>>>(wsrc[w], WBF + (size_t)w * 589824);
  k_pos<<<MSW / 4, blk, 0, stream>>>(s_idx, GIDX, MASK);
  k_gather<<<24576, blk, 0, stream>>>(sent_embed, GIDX, WEbf);

  // 1) Q,K projections + attention
  k_mgemm<<<gG, blk, 0, stream>>>(WEbf, nullptr, WBF + 0 * 589824, wq_b, nullptr,
                                  WSA, nullptr, MSW, 0);
  k_mgemm<<<gG, blk, 0, stream>>>(WEbf, nullptr, WBF + 1 * 589824, wk_b, nullptr,
                                  WSB, nullptr, MSW, 0);
  k_attn<<<SS, blk, 0, stream>>>(WSA, WSB, MASK, LATJ);

  // 2) gated GCN layer 1
  k_mgemm<<<gG, blk, 0, stream>>>(WEbf, nullptr, WBF + 2 * 589824, nullptr, nullptr,
                                  WSA, nullptr, MSW, 0);
  k_dualadj<<<dim3(12, SS), blk, 0, stream>>>(dep_adj, LATJ, WSA, OdBF, OlBF);
  k_mgemm<<<gG, blk, 0, stream>>>(OdBF, nullptr, WBF + 3 * 589824, gc1_l1b, nullptr,
                                  WSA, nullptr, MSW, 0);
  k_mgemm<<<gG, blk, 0, stream>>>(OlBF, nullptr, WBF + 4 * 589824, gc1_l2b, WSA,
                                  WSA, nullptr, MSW, 0);
  k_gate<<<24576, blk, 0, stream>>>(WSA, OdBF, OlBF, gc1_b, WEbf);  // x1 -> WEbf

  // 3) gated GCN layer 2
  k_mgemm<<<gG, blk, 0, stream>>>(WEbf, nullptr, WBF + 5 * 589824, nullptr, nullptr,
                                  WSA, nullptr, MSW, 0);
  k_dualadj<<<dim3(12, SS), blk, 0, stream>>>(dep_adj, LATJ, WSA, OdBF, OlBF);
  k_mgemm<<<gG, blk, 0, stream>>>(OdBF, nullptr, WBF + 6 * 589824, gc2_l1b, nullptr,
                                  WSA, nullptr, MSW, 0);
  k_mgemm<<<gG, blk, 0, stream>>>(OlBF, nullptr, WBF + 7 * 589824, gc2_l2b, WSA,
                                  WSA, nullptr, MSW, 0);
  k_gate<<<24576, blk, 0, stream>>>(WSA, OdBF, OlBF, gc2_b, WEbf);  // x2 -> WEbf
  k_resadd<<<24576, blk, 0, stream>>>(WEbf, sent_embed, GIDX);

  // 4) node features
  k_feats<<<6529, blk, 0, stream>>>(doc_cls, sent_cls, t_sid, t_index, WEbf, FfeatBF);

  // 5) two relational GCN layers
  const ushort* rinBF[2] = {FfeatBF, H1BF};
  ushort* routBF[2] = {H1BF, H2BF};
  const float* relb[2] = {rel1_b, rel2_b};
  const int wrel[2] = {8, 13};   // WBF indices of rel_w[0]
  const int wloop[2] = {12, 17};
  for (int l = 0; l < 2; ++l) {
    hipMemsetAsync(HSUM, 0, NODE_F * sizeof(float), stream);
    for (int r = 0; r < 4; ++r) {
      hipMemsetAsync(AGG, 0, NODE_F * sizeof(float), stream);
      hipMemsetAsync(DEG, 0, NN * sizeof(float), stream);
      k_mgemm<<<gE, blk, 0, stream>>>(rinBF[l], e_src + r * EG,
                                      WBF + (size_t)(wrel[l] + r) * 589824,
                                      nullptr, nullptr, MSG, nullptr, EG, 0);
      k_deg<<<EG / 256, blk, 0, stream>>>(e_dst + r * EG, DEG);
      k_scatter<<<((size_t)EG * DD) / 256, blk, 0, stream>>>(e_dst + r * EG, MSG, AGG);
      k_accum<<<6529, blk, 0, stream>>>(AGG, DEG, HSUM);
    }
    k_mgemm<<<gN, blk, 0, stream>>>(rinBF[l], nullptr,
                                    WBF + (size_t)wloop[l] * 589824, relb[l], HSUM,
                                    nullptr, routBF[l], NN, 1);
  }

  // 6) predictor
  k_pred<<<NN, blk, 0, stream>>>(FfeatBF, H1BF, H2BF, pred_w, pred_b, out);
}

// Round 3
// 2463.813 us; speedup vs baseline: 2.7161x; 1.0127x over previous
//
#include <hip/hip_runtime.h>
#include <math.h>

// Problem constants
#define SS 512
#define LL 128
#define WW 64
#define DD 768
#define EG 8192
#define NN 8705          // 1 + S + T
#define MSW 32768        // S*W
#define NODE_F 6685440   // NN*DD
#define WSZ 589824       // DD*DD

typedef __attribute__((ext_vector_type(8))) short bf16x8;
typedef __attribute__((ext_vector_type(4))) float f32x4;

__device__ __forceinline__ ushort f2bf(float f) {
  union { float f; unsigned u; } v; v.f = f;
  unsigned r = (v.u + 0x7FFF + ((v.u >> 16) & 1)) >> 16;
  return (ushort)r;
}
__device__ __forceinline__ float bf2f(ushort b) {
  union { unsigned u; float f; } v; v.u = ((unsigned)b) << 16;
  return v.f;
}
__device__ __forceinline__ void gload16(const void* g, void* l) {
  __builtin_amdgcn_global_load_lds(
      (const __attribute__((address_space(1))) void*)g,
      (__attribute__((address_space(3))) void*)l, 16, 0, 0);
}

// ---------------------------------------------------------------------------
// gidx from one-hot s_idx (mask is provably all-ones: pos always in [0,L))
__global__ __launch_bounds__(256) void k_pos(const float* __restrict__ s_idx,
                                             int* __restrict__ gidx) {
  int row = blockIdx.x * 4 + (threadIdx.x >> 6);
  int lane = threadIdx.x & 63;
  const float* p = s_idx + (size_t)row * LL;
  float v0 = p[lane], v1 = p[lane + 64];
  int idx = v0 > 0.5f ? lane : (v1 > 0.5f ? lane + 64 : -1);
#pragma unroll
  for (int off = 32; off; off >>= 1) {
    int o = __shfl_xor(idx, off, 64);
    idx = o > idx ? o : idx;
  }
  if (lane == 0) {
    int s = row >> 6;
    gidx[row] = s * LL + (idx < 0 ? 0 : idx);
  }
}

// all 18 weight matrices: fp32 [768][768] -> bf16 transposed [N][K], one dispatch
struct WP { const float* p[18]; };
__global__ __launch_bounds__(256) void k_wtall(WP wp, ushort* __restrict__ dst0) {
  __shared__ float t[32][33];
  int w = blockIdx.x / 576, b = blockIdx.x % 576;
  const float* src = wp.p[w];
  ushort* dst = dst0 + (size_t)w * WSZ;
  int bx = b % 24, by = b / 24;
  int r0 = by * 32, c0 = bx * 32;
  int lx = threadIdx.x & 31, ly = threadIdx.x >> 5;
#pragma unroll
  for (int i = 0; i < 4; ++i)
    t[ly + i * 8][lx] = src[(size_t)(r0 + ly + i * 8) * DD + c0 + lx];
  __syncthreads();
#pragma unroll
  for (int i = 0; i < 4; ++i)
    dst[(size_t)(c0 + ly + i * 8) * DD + r0 + lx] = f2bf(t[lx][ly + i * 8]);
}

// gather word embeddings -> bf16 [MSW,768]
__global__ __launch_bounds__(256) void k_gather(const float* __restrict__ SE,
                                                const int* __restrict__ gidx,
                                                ushort* __restrict__ WE) {
  size_t i = (size_t)blockIdx.x * 256 + threadIdx.x;
  size_t row = i / 192, q = i % 192;
  float4 v = ((const float4*)(SE + (size_t)gidx[row] * DD))[q];
  ushort4 o;
  o.x = f2bf(v.x); o.y = f2bf(v.y); o.z = f2bf(v.z); o.w = f2bf(v.w);
  ((ushort4*)WE)[i] = o;
}

// ---------------------------------------------------------------------------
// bf16 MFMA GEMM body: C[M,768] = act(gather(A)[M,768] @ BT^T + bias + addC)
__device__ __forceinline__ void mgemm_body(
    const ushort* __restrict__ A, const int* __restrict__ rowidx,
    const ushort* __restrict__ BT, const float* __restrict__ bias,
    const float* __restrict__ addCf, const ushort* __restrict__ addCb,
    float* __restrict__ Cf, ushort* __restrict__ Cb,
    int M, int relu, int bm, int bn, ushort* As, ushort* Bs) {
  const int tid = threadIdx.x;
  const int wave = tid >> 6, lane = tid & 63;
  const int lrow = lane & 15, quad = lane >> 4;

  const ushort* gA[4];
  const ushort* gB[4];
#pragma unroll
  for (int j = 0; j < 4; ++j) {
    int c = (wave * 4 + j) * 64 + lane;
    int row = c >> 3, kslot = c & 7;
    int kb = kslot ^ (row & 7);
    int ar = bm + row; ar = ar < M ? ar : M - 1;
    int agr = rowidx ? rowidx[ar] : ar;
    gA[j] = A + (size_t)agr * DD + kb * 8;
    gB[j] = BT + (size_t)(bn + row) * DD + kb * 8;
  }

  f32x4 acc[4][4];
#pragma unroll
  for (int i = 0; i < 4; ++i)
#pragma unroll
    for (int j = 0; j < 4; ++j) acc[i][j] = (f32x4){0.f, 0.f, 0.f, 0.f};

  const int wm = (wave >> 1) * 64, wn = (wave & 1) * 64;

  for (int kt = 0; kt < 12; ++kt) {
#pragma unroll
    for (int j = 0; j < 4; ++j) {
      gload16(gA[j], &As[(wave * 4 + j) * 512]);
      gload16(gB[j], &Bs[(wave * 4 + j) * 512]);
      gA[j] += 64;
      gB[j] += 64;
    }
    __syncthreads();
#pragma unroll
    for (int ks = 0; ks < 2; ++ks) {
      bf16x8 af[4], bfr[4];
#pragma unroll
      for (int mi = 0; mi < 4; ++mi) {
        int r = wm + mi * 16 + lrow;
        int kc = ks * 4 + quad;
        af[mi] = *(const bf16x8*)&As[r * 64 + ((kc ^ (r & 7)) * 8)];
      }
#pragma unroll
      for (int ni = 0; ni < 4; ++ni) {
        int r = wn + ni * 16 + lrow;
        int kc = ks * 4 + quad;
        bfr[ni] = *(const bf16x8*)&Bs[r * 64 + ((kc ^ (r & 7)) * 8)];
      }
#pragma unroll
      for (int mi = 0; mi < 4; ++mi)
#pragma unroll
        for (int ni = 0; ni < 4; ++ni)
          acc[mi][ni] = __builtin_amdgcn_mfma_f32_16x16x32_bf16(
              af[mi], bfr[ni], acc[mi][ni], 0, 0, 0);
    }
    __syncthreads();
  }

#pragma unroll
  for (int mi = 0; mi < 4; ++mi) {
#pragma unroll
    for (int ni = 0; ni < 4; ++ni) {
      f32x4 v = acc[mi][ni];
      int col = bn + wn + ni * 16 + lrow;
      float bv = bias ? bias[col] : 0.f;
#pragma unroll
      for (int r = 0; r < 4; ++r) {
        int grow = bm + wm + mi * 16 + quad * 4 + r;
        if (grow >= M) continue;
        size_t off = (size_t)grow * DD + col;
        float t = v[r] + bv;
        if (addCf) t += addCf[off];
        if (addCb) t += bf2f(addCb[off]);
        if (relu) t = fmaxf(t, 0.f);
        if (Cb) Cb[off] = f2bf(t);
        else Cf[off] = t;
      }
    }
  }
}

__global__ __launch_bounds__(256) void k_mgemm(
    const ushort* __restrict__ A, const int* __restrict__ rowidx,
    const ushort* __restrict__ BT, const float* __restrict__ bias,
    const float* __restrict__ addCf, const ushort* __restrict__ addCb,
    float* __restrict__ Cf, ushort* __restrict__ Cb, int M, int relu) {
  __shared__ ushort As[8192], Bs[8192];
  mgemm_body(A, rowidx, BT, bias, addCf, addCb, Cf, Cb, M, relu,
             blockIdx.y * 128, blockIdx.x * 128, As, Bs);
}

// fused Q,K projection: grid (12, 256); x<6 -> Q, x>=6 -> K
__global__ __launch_bounds__(256) void k_mgemm_qk(
    const ushort* __restrict__ A, const ushort* __restrict__ BTq,
    const ushort* __restrict__ BTk, const float* __restrict__ bq,
    const float* __restrict__ bk, ushort* __restrict__ Qb,
    ushort* __restrict__ Kb) {
  __shared__ ushort As[8192], Bs[8192];
  int sel = blockIdx.x >= 6;
  mgemm_body(A, nullptr, sel ? BTk : BTq, sel ? bk : bq, nullptr, nullptr,
             nullptr, sel ? Kb : Qb, MSW, 0,
             blockIdx.y * 128, (blockIdx.x - sel * 6) * 128, As, Bs);
}

// batched per-relation edge message GEMM: grid (6, 64, 4)
__global__ __launch_bounds__(256) void k_mgemm_edge(
    const ushort* __restrict__ A, const int* __restrict__ esrc,
    const ushort* __restrict__ BT0, ushort* __restrict__ Cb0) {
  __shared__ ushort As[8192], Bs[8192];
  int z = blockIdx.z;
  mgemm_body(A, esrc + z * EG, BT0 + (size_t)z * WSZ, nullptr, nullptr, nullptr,
             nullptr, Cb0 + (size_t)z * EG * DD, EG, 0,
             blockIdx.y * 128, blockIdx.x * 128, As, Bs);
}

// ---------------------------------------------------------------------------
// Attention (MFMA QK^T) + exact entmax-1.5 -> latent adjacency (atomic acc).
// grid (SS, 4): blockIdx.y = head-pair; 256 threads; wave wv owns rows wv*16..+15
__global__ __launch_bounds__(256) void k_attn(const ushort* __restrict__ Q,
                                              const ushort* __restrict__ K,
                                              float* __restrict__ lat) {
  __shared__ __align__(16) ushort qs[64 * 96];
  __shared__ __align__(16) ushort ks[64 * 96];
  const int s = blockIdx.x, hp = blockIdx.y;
  const int tid = threadIdx.x;
  const int wv = tid >> 6, lane = tid & 63;
  const int lrow = lane & 15, quad = lane >> 4;
  const int m0 = wv * 16;
  const float SC2 = 0.05103103630798288f;  // 0.5 / sqrt(96)

  float regacc[16];
#pragma unroll
  for (int i = 0; i < 16; ++i) regacc[i] = 0.f;

  for (int hh = 0; hh < 2; ++hh) {
    const int h = hp * 2 + hh;
    __syncthreads();
#pragma unroll
    for (int j = 0; j < 3; ++j) {
      int c = (j * 4 + wv) * 64 + lane;
      int row = c / 12, o = c % 12;
      const ushort* gq = Q + (size_t)(s * 64 + row) * DD + h * 96 + o * 8;
      const ushort* gk = K + (size_t)(s * 64 + row) * DD + h * 96 + o * 8;
      gload16(gq, &qs[(j * 4 + wv) * 512]);
      gload16(gk, &ks[(j * 4 + wv) * 512]);
    }
    __syncthreads();

    // scores rows m0..m0+15 x cols 0..63 via MFMA
    f32x4 acc4[4];
#pragma unroll
    for (int t = 0; t < 4; ++t) acc4[t] = (f32x4){0.f, 0.f, 0.f, 0.f};
#pragma unroll
    for (int k = 0; k < 3; ++k) {
      bf16x8 a = *(const bf16x8*)&qs[(m0 + lrow) * 96 + k * 32 + quad * 8];
#pragma unroll
      for (int t = 0; t < 4; ++t) {
        bf16x8 b = *(const bf16x8*)&ks[(t * 16 + lrow) * 96 + k * 32 + quad * 8];
        acc4[t] = __builtin_amdgcn_mfma_f32_16x16x32_bf16(a, b, acc4[t], 0, 0, 0);
      }
    }

    // per row: redistribute C layout -> lane=col, then entmax-1.5
#pragma unroll
    for (int r = 0; r < 16; ++r) {
      int srcl = (r >> 2) * 16 + lrow;
      float t0 = __shfl(acc4[0][r & 3], srcl, 64);
      float t1 = __shfl(acc4[1][r & 3], srcl, 64);
      float t2 = __shfl(acc4[2][r & 3], srcl, 64);
      float t3 = __shfl(acc4[3][r & 3], srcl, 64);
      float xv = quad == 0 ? t0 : quad == 1 ? t1 : quad == 2 ? t2 : t3;
      float x = xv * SC2;
      // bitonic sort descending across 64 lanes
      float z = x;
      for (int k = 2; k <= 64; k <<= 1)
        for (int j = k >> 1; j; j >>= 1) {
          float o = __shfl_xor(z, j, 64);
          bool lower = (lane & j) == 0;
          bool takeMax = ((lane & k) == 0) ? lower : !lower;
          z = takeMax ? fmaxf(z, o) : fminf(z, o);
        }
      float zmax = __shfl(z, 0, 64);
      z -= zmax;
      float xs = x - zmax;
      float cz = z, czz = z * z;
      for (int off = 1; off < 64; off <<= 1) {
        float t1s = __shfl_up(cz, off, 64);
        float t2s = __shfl_up(czz, off, 64);
        if (lane >= off) { cz += t1s; czz += t2s; }
      }
      float kk = (float)(lane + 1);
      float mean = cz / kk;
      float ssv = kk * (czz / kk - mean * mean);
      float delta = (1.f - ssv) / kk;
      float sq = delta > 0.f ? sqrtf(delta) : 0.f;
      float tau = mean - sq;
      unsigned long long bal = __ballot(tau <= z);
      int support = __popcll(bal);
      float tau_star = __shfl(tau, support - 1, 64);
      float p = fmaxf(xs - tau_star, 0.f);
      regacc[r] += p * p;
    }
  }
#pragma unroll
  for (int r = 0; r < 16; ++r)
    atomicAdd(&lat[((size_t)s * 64 + m0 + r) * 64 + lane], regacc[r] * 0.125f);
}

// ---------------------------------------------------------------------------
// Od[s]=dep[s]@Hh[s], Ol[s]=lat[s]@Hh[s]; Hh bf16 in, bf16 out
__global__ __launch_bounds__(256) void k_dualadj(const float* __restrict__ dep,
                                                 const float* __restrict__ lat,
                                                 const ushort* __restrict__ Hh,
                                                 ushort* __restrict__ Od,
                                                 ushort* __restrict__ Ol) {
  __shared__ float Pd[64][68];
  __shared__ float Pl[64][68];
  __shared__ float Hc[64][68];
  const int s = blockIdx.y;
  const int c0 = blockIdx.x * 64;
  const int tid = threadIdx.x;
  const int tx = tid & 15, ty = tid >> 4;
  for (int i = tid; i < 4096; i += 256) {
    int r = i >> 6, c = i & 63;
    Pd[r][c] = dep[(size_t)s * 4096 + i];
    Pl[r][c] = lat[(size_t)s * 4096 + i];
  }
  for (int i = tid; i < 1024; i += 256) {
    int r = i >> 4, f = i & 15;
    ushort4 u = *(const ushort4*)(Hh + (size_t)(s * 64 + r) * DD + c0 + f * 4);
    Hc[r][f * 4 + 0] = bf2f(u.x);
    Hc[r][f * 4 + 1] = bf2f(u.y);
    Hc[r][f * 4 + 2] = bf2f(u.z);
    Hc[r][f * 4 + 3] = bf2f(u.w);
  }
  __syncthreads();
  float ad[4][4] = {}, al[4][4] = {};
  for (int w2 = 0; w2 < 64; ++w2) {
    float4 b4 = *(const float4*)&Hc[w2][tx * 4];
    float bb[4] = {b4.x, b4.y, b4.z, b4.w};
    float pd[4], pl[4];
#pragma unroll
    for (int i = 0; i < 4; ++i) {
      pd[i] = Pd[ty * 4 + i][w2];
      pl[i] = Pl[ty * 4 + i][w2];
    }
#pragma unroll
    for (int i = 0; i < 4; ++i)
#pragma unroll
      for (int j = 0; j < 4; ++j) {
        ad[i][j] = fmaf(pd[i], bb[j], ad[i][j]);
        al[i][j] = fmaf(pl[i], bb[j], al[i][j]);
      }
  }
#pragma unroll
  for (int i = 0; i < 4; ++i) {
    size_t ro = (size_t)(s * 64 + ty * 4 + i) * DD + c0 + tx * 4;
    ushort4 vd, vl;
    vd.x = f2bf(ad[i][0]); vd.y = f2bf(ad[i][1]);
    vd.z = f2bf(ad[i][2]); vd.w = f2bf(ad[i][3]);
    vl.x = f2bf(al[i][0]); vl.y = f2bf(al[i][1]);
    vl.z = f2bf(al[i][2]); vl.w = f2bf(al[i][3]);
    *(ushort4*)&Od[ro] = vd;
    *(ushort4*)&Ol[ro] = vl;
  }
}

// gated fusion (+ optional fused residual add of word_embed)
__global__ __launch_bounds__(256) void k_gate(const ushort* __restrict__ g1,
                                              const ushort* __restrict__ om,
                                              const ushort* __restrict__ lm,
                                              const float* __restrict__ bias,
                                              const float* __restrict__ SE,
                                              const int* __restrict__ gidx,
                                              int fuse_res,
                                              ushort* __restrict__ dst) {
  size_t i = (size_t)blockIdx.x * 256 + threadIdx.x;  // 4-elem units
  ushort4 g4 = ((const ushort4*)g1)[i];
  ushort4 o4 = ((const ushort4*)om)[i];
  ushort4 l4 = ((const ushort4*)lm)[i];
  int col = (int)((i * 4) % DD);
  size_t row = i / 192;
  float4 res = make_float4(0.f, 0.f, 0.f, 0.f);
  if (fuse_res) res = ((const float4*)(SE + (size_t)gidx[row] * DD))[i % 192];
  float gv[4] = {bf2f(g4.x), bf2f(g4.y), bf2f(g4.z), bf2f(g4.w)};
  float ov[4] = {bf2f(o4.x), bf2f(o4.y), bf2f(o4.z), bf2f(o4.w)};
  float lv[4] = {bf2f(l4.x), bf2f(l4.y), bf2f(l4.z), bf2f(l4.w)};
  float rv[4] = {res.x, res.y, res.z, res.w};
  ushort4 r;
  ushort* rr = (ushort*)&r;
#pragma unroll
  for (int j = 0; j < 4; ++j) {
    float g = 1.f / (1.f + expf(-gv[j]));
    float v = g * ov[j] + (1.f - g) * lv[j] + bias[col + j];
    rr[j] = f2bf(fmaxf(v, 0.f) + rv[j]);
  }
  ((ushort4*)dst)[i] = r;
}

// node feature assembly -> bf16 [NN,768]
__global__ __launch_bounds__(256) void k_feats(const float* __restrict__ doc,
                                               const float* __restrict__ scls,
                                               const int* __restrict__ t_sid,
                                               const int* __restrict__ t_index,
                                               const ushort* __restrict__ X,
                                               ushort* __restrict__ F) {
  size_t i = (size_t)blockIdx.x * 256 + threadIdx.x;
  if (i >= (size_t)NN * 192) return;
  size_t n = i / 192, q = i % 192;
  ushort4 o;
  if (n <= SS) {
    float4 v = (n == 0) ? ((const float4*)doc)[q]
                        : ((const float4*)scls)[(n - 1) * 192 + q];
    o.x = f2bf(v.x); o.y = f2bf(v.y); o.z = f2bf(v.z); o.w = f2bf(v.w);
  } else {
    size_t t = n - 1 - SS;
    size_t row = (size_t)t_sid[t] * WW + t_index[t];
    o = ((const ushort4*)X)[row * 192 + q];
  }
  ((ushort4*)F)[i] = o;
}

// per-relation degree (shared by both layers), then reciprocal
__global__ __launch_bounds__(256) void k_deg4(const int* __restrict__ dstAll,
                                              float* __restrict__ deg4) {
  int i = blockIdx.x * 256 + threadIdx.x;  // 0..4*EG
  int rel = i / EG;
  atomicAdd(&deg4[rel * NN + dstAll[i]], 1.f);
}
__global__ __launch_bounds__(256) void k_rcp(float* __restrict__ deg4) {
  int i = blockIdx.x * 256 + threadIdx.x;
  if (i < 4 * NN) deg4[i] = 1.f / fmaxf(deg4[i], 1.f);
}

// scatter msg/deg into HSUM (all 4 relations, one dispatch)
__global__ __launch_bounds__(256) void k_scatter2(const ushort* __restrict__ msg,
                                                  const int* __restrict__ dstAll,
                                                  const float* __restrict__ rdeg4,
                                                  float* __restrict__ hsum) {
  size_t i = (size_t)blockIdx.x * 256 + threadIdx.x;  // 4-elem units, 4*EG*192
  const int perRel = EG * 192;
  int rel = (int)(i / perRel);
  int rem = (int)(i - (size_t)rel * perRel);
  int e = rem / 192, q = rem - (rem / 192) * 192;
  int node = dstAll[rel * EG + e];
  float rd = rdeg4[rel * NN + node];
  ushort4 m4 = ((const ushort4*)msg)[i];
  float* hp = &hsum[(size_t)node * DD + q * 4];
  atomicAdd(hp + 0, bf2f(m4.x) * rd);
  atomicAdd(hp + 1, bf2f(m4.y) * rd);
  atomicAdd(hp + 2, bf2f(m4.z) * rd);
  atomicAdd(hp + 3, bf2f(m4.w) * rd);
}

// final predictor from bf16 bank
__global__ __launch_bounds__(256) void k_pred(const ushort* __restrict__ F,
                                              const ushort* __restrict__ h1,
                                              const ushort* __restrict__ h2,
                                              const float* __restrict__ pw,
                                              const float* __restrict__ pb,
                                              float* __restrict__ out) {
  const int n = blockIdx.x;
  const int tid = threadIdx.x;
  float acc[5] = {};
  for (int k = tid; k < 3 * DD; k += 256) {
    float v;
    if (k < DD) v = bf2f(F[(size_t)n * DD + k]);
    else if (k < 2 * DD) v = bf2f(h1[(size_t)n * DD + k - DD]);
    else v = bf2f(h2[(size_t)n * DD + k - 2 * DD]);
    const float* w = pw + (size_t)k * 5;
#pragma unroll
    for (int o = 0; o < 5; ++o) acc[o] = fmaf(v, w[o], acc[o]);
  }
#pragma unroll
  for (int o = 0; o < 5; ++o)
    for (int off = 32; off; off >>= 1) acc[o] += __shfl_xor(acc[o], off, 64);
  __shared__ float red[5][4];
  const int wv = tid >> 6, lane = tid & 63;
  if (lane == 0)
#pragma unroll
    for (int o = 0; o < 5; ++o) red[o][wv] = acc[o];
  __syncthreads();
  if (tid == 0)
#pragma unroll
    for (int o = 0; o < 5; ++o)
      out[(size_t)n * 5 + o] = red[o][0] + red[o][1] + red[o][2] + red[o][3] + pb[o];
}

// ---------------------------------------------------------------------------
extern "C" void kernel_launch(void* const* d_in, const int* in_sizes, int n_in,
                              void* d_out, int out_size, void* d_ws, size_t ws_size,
                              hipStream_t stream) {
  const float* sent_embed = (const float*)d_in[0];
  const float* s_idx      = (const float*)d_in[1];
  const float* dep_adj    = (const float*)d_in[2];
  const float* doc_cls    = (const float*)d_in[3];
  const float* sent_cls   = (const float*)d_in[4];
  const int*   t_sid      = (const int*)d_in[5];
  const int*   t_index    = (const int*)d_in[6];
  const int*   e_src      = (const int*)d_in[7];
  const int*   e_dst      = (const int*)d_in[8];
  WP wp;
  wp.p[0] = (const float*)d_in[9];   // wq
  wp.p[1] = (const float*)d_in[11];  // wk
  wp.p[2] = (const float*)d_in[13];  // gc1_w
  wp.p[3] = (const float*)d_in[15];  // gc1_l1w
  wp.p[4] = (const float*)d_in[17];  // gc1_l2w
  wp.p[5] = (const float*)d_in[19];  // gc2_w
  wp.p[6] = (const float*)d_in[21];  // gc2_l1w
  wp.p[7] = (const float*)d_in[23];  // gc2_l2w
  for (int r = 0; r < 4; ++r) {
    wp.p[8 + r]  = (const float*)d_in[25] + (size_t)r * WSZ;  // rel1_w
    wp.p[13 + r] = (const float*)d_in[28] + (size_t)r * WSZ;  // rel2_w
  }
  wp.p[12] = (const float*)d_in[26];  // rel1_loop
  wp.p[17] = (const float*)d_in[29];  // rel2_loop
  const float* wq_b = (const float*)d_in[10];
  const float* wk_b = (const float*)d_in[12];
  const float* gc1_b   = (const float*)d_in[14];
  const float* gc1_l1b = (const float*)d_in[16];
  const float* gc1_l2b = (const float*)d_in[18];
  const float* gc2_b   = (const float*)d_in[20];
  const float* gc2_l1b = (const float*)d_in[22];
  const float* gc2_l2b = (const float*)d_in[24];
  const float* rel1_b = (const float*)d_in[27];
  const float* rel2_b = (const float*)d_in[30];
  const float* pred_w = (const float*)d_in[31];
  const float* pred_b = (const float*)d_in[32];
  float* out = (float*)d_out;

  // workspace carve (bytes), total ~231 MB
  char* W = (char*)d_ws;
  ushort* WEbf = (ushort*)W;                       // 50331648 B
  char* B1 = W + 50331648;
  char* B2 = B1 + 50331648;
  char* B3 = B2 + 50331648;
  float* LATJ = (float*)(B3 + 50331648);           // 8388608 B
  int* GIDX = (int*)((char*)LATJ + 8388608);       // 131072 B
  float* RDEG = (float*)((char*)GIDX + 131072);    // 139520 B
  ushort* WBF = (ushort*)((char*)RDEG + 139520);   // 21233664 B

  ushort* Qbf = (ushort*)B1;
  ushort* Kbf = (ushort*)B2;
  ushort* Hh  = (ushort*)B1;
  ushort* Od  = (ushort*)B2;
  ushort* Ol  = (ushort*)B3;
  ushort* G1  = (ushort*)B1;
  ushort* Ffeat = (ushort*)B1;
  ushort* H1 = Ffeat + NODE_F;
  ushort* H2 = Ffeat + 2 * (size_t)NODE_F;
  ushort* MSG = (ushort*)B2;        // 4*EG*DD bf16 = 50331648 B
  float* HSUM = (float*)B3;         // NODE_F fp32 = 26.7 MB

  dim3 blk(256);

  // 0) prep
  k_wtall<<<18 * 576, blk, 0, stream>>>(wp, WBF);
  k_pos<<<MSW / 4, blk, 0, stream>>>(s_idx, GIDX);
  k_gather<<<24576, blk, 0, stream>>>(sent_embed, GIDX, WEbf);
  hipMemsetAsync(LATJ, 0, 8388608, stream);
  hipMemsetAsync(RDEG, 0, 4 * NN * sizeof(float), stream);
  k_deg4<<<4 * EG / 256, blk, 0, stream>>>(e_dst, RDEG);
  k_rcp<<<(4 * NN + 255) / 256, blk, 0, stream>>>(RDEG);

  // 1) Q,K projections (one dispatch) + attention
  k_mgemm_qk<<<dim3(12, 256), blk, 0, stream>>>(WEbf, WBF + 0 * (size_t)WSZ,
                                                WBF + 1 * (size_t)WSZ, wq_b, wk_b,
                                                Qbf, Kbf);
  k_attn<<<dim3(SS, 4), blk, 0, stream>>>(Qbf, Kbf, LATJ);

  // 2) gated GCN layers
  const int wIdx[2][3] = {{2, 3, 4}, {5, 6, 7}};
  const float* l1b[2] = {gc1_l1b, gc2_l1b};
  const float* l2b[2] = {gc1_l2b, gc2_l2b};
  const float* gb[2] = {gc1_b, gc2_b};
  for (int l = 0; l < 2; ++l) {
    k_mgemm<<<dim3(6, 256), blk, 0, stream>>>(WEbf, nullptr,
        WBF + (size_t)wIdx[l][0] * WSZ, nullptr, nullptr, nullptr,
        nullptr, Hh, MSW, 0);
    k_dualadj<<<dim3(12, SS), blk, 0, stream>>>(dep_adj, LATJ, Hh, Od, Ol);
    k_mgemm<<<dim3(6, 256), blk, 0, stream>>>(Od, nullptr,
        WBF + (size_t)wIdx[l][1] * WSZ, l1b[l], nullptr, nullptr,
        nullptr, G1, MSW, 0);
    k_mgemm<<<dim3(6, 256), blk, 0, stream>>>(Ol, nullptr,
        WBF + (size_t)wIdx[l][2] * WSZ, l2b[l], nullptr, G1,
        nullptr, G1, MSW, 0);
    k_gate<<<24576, blk, 0, stream>>>(G1, Od, Ol, gb[l], sent_embed, GIDX,
                                      l == 1 ? 1 : 0, WEbf);
  }

  // 3) node features
  k_feats<<<6529, blk, 0, stream>>>(doc_cls, sent_cls, t_sid, t_index, WEbf, Ffeat);

  // 4) two relational GCN layers
  const ushort* rin[2] = {Ffeat, H1};
  ushort* rout[2] = {H1, H2};
  const float* relb[2] = {rel1_b, rel2_b};
  const int wrel[2] = {8, 13};
  const int wloop[2] = {12, 17};
  for (int l = 0; l < 2; ++l) {
    hipMemsetAsync(HSUM, 0, (size_t)NODE_F * sizeof(float), stream);
    k_mgemm_edge<<<dim3(6, 64, 4), blk, 0, stream>>>(
        rin[l], e_src, WBF + (size_t)wrel[l] * WSZ, MSG);
    k_scatter2<<<24576, blk, 0, stream>>>(MSG, e_dst, RDEG, HSUM);
    k_mgemm<<<dim3(6, 69), blk, 0, stream>>>(rin[l], nullptr,
        WBF + (size_t)wloop[l] * WSZ, relb[l], HSUM, nullptr,
        nullptr, rout[l], NN, 1);
  }

  // 5) predictor
  k_pred<<<NN, blk, 0, stream>>>(Ffeat, H1, H2, pred_w, pred_b, out);
}

// Round 4
// 1785.443 us; speedup vs baseline: 3.7481x; 1.3799x over previous
//
#include <hip/hip_runtime.h>
#include <math.h>

// Problem constants
#define SS 512
#define LL 128
#define WW 64
#define DD 768
#define EG 8192
#define NN 8705          // 1 + S + T
#define MSW 32768        // S*W
#define NODE_F 6685440   // NN*DD
#define WSZ 589824       // DD*DD
#define KREL 3840        // 5*DD (feats | pre_agg x4)
#define NPAIR 34820      // 4*NN

typedef __attribute__((ext_vector_type(8))) short bf16x8;
typedef __attribute__((ext_vector_type(4))) float f32x4;

__device__ __forceinline__ ushort f2bf(float f) {
  union { float f; unsigned u; } v; v.f = f;
  unsigned r = (v.u + 0x7FFF + ((v.u >> 16) & 1)) >> 16;
  return (ushort)r;
}
__device__ __forceinline__ float bf2f(ushort b) {
  union { unsigned u; float f; } v; v.u = ((unsigned)b) << 16;
  return v.f;
}
__device__ __forceinline__ void gload16(const void* g, void* l) {
  __builtin_amdgcn_global_load_lds(
      (const __attribute__((address_space(1))) void*)g,
      (__attribute__((address_space(3))) void*)l, 16, 0, 0);
}

// ---------------------------------------------------------------------------
__global__ __launch_bounds__(256) void k_pos(const float* __restrict__ s_idx,
                                             int* __restrict__ gidx) {
  int row = blockIdx.x * 4 + (threadIdx.x >> 6);
  int lane = threadIdx.x & 63;
  const float* p = s_idx + (size_t)row * LL;
  float v0 = p[lane], v1 = p[lane + 64];
  int idx = v0 > 0.5f ? lane : (v1 > 0.5f ? lane + 64 : -1);
#pragma unroll
  for (int off = 32; off; off >>= 1) {
    int o = __shfl_xor(idx, off, 64);
    idx = o > idx ? o : idx;
  }
  if (lane == 0) {
    int s = row >> 6;
    gidx[row] = s * LL + (idx < 0 ? 0 : idx);
  }
}

// weight transpose/convert: src fp32 [768][768] -> dst bf16 [N][K-stride]
struct WTJob { const float* src; ushort* dst; long stride; };
struct WTJobs { WTJob j[18]; };
__global__ __launch_bounds__(256) void k_wtall(WTJobs wj) {
  __shared__ float t[32][33];
  int w = blockIdx.x / 576, b = blockIdx.x % 576;
  const float* src = wj.j[w].src;
  ushort* dst = wj.j[w].dst;
  long stride = wj.j[w].stride;
  int bx = b % 24, by = b / 24;
  int r0 = by * 32, c0 = bx * 32;
  int lx = threadIdx.x & 31, ly = threadIdx.x >> 5;
#pragma unroll
  for (int i = 0; i < 4; ++i)
    t[ly + i * 8][lx] = src[(size_t)(r0 + ly + i * 8) * DD + c0 + lx];
  __syncthreads();
#pragma unroll
  for (int i = 0; i < 4; ++i)
    dst[(size_t)(c0 + ly + i * 8) * stride + r0 + lx] = f2bf(t[lx][ly + i * 8]);
}

// gather word embeddings -> bf16 [MSW,768]
__global__ __launch_bounds__(256) void k_gather(const float* __restrict__ SE,
                                                const int* __restrict__ gidx,
                                                ushort* __restrict__ WE) {
  size_t i = (size_t)blockIdx.x * 256 + threadIdx.x;
  size_t row = i / 192, q = i % 192;
  float4 v = ((const float4*)(SE + (size_t)gidx[row] * DD))[q];
  ushort4 o;
  o.x = f2bf(v.x); o.y = f2bf(v.y); o.z = f2bf(v.z); o.w = f2bf(v.w);
  ((ushort4*)WE)[i] = o;
}

// ---------------------------------------------------------------------------
// CSR-by-destination build
__global__ __launch_bounds__(256) void k_deg4(const int* __restrict__ dstAll,
                                              int* __restrict__ degc) {
  int i = blockIdx.x * 256 + threadIdx.x;  // 0..4*EG
  int rel = i >> 13;
  atomicAdd(&degc[rel * NN + dstAll[i]], 1);
}
__global__ __launch_bounds__(256) void k_rcp(const int* __restrict__ degc,
                                             float* __restrict__ rdeg) {
  int i = blockIdx.x * 256 + threadIdx.x;
  if (i < NPAIR) rdeg[i] = 1.f / fmaxf((float)degc[i], 1.f);
}
__global__ __launch_bounds__(1024) void k_scan(const int* __restrict__ cnt,
                                               int* __restrict__ offs) {
  __shared__ int part[1024];
  const int tid = threadIdx.x;
  const int C = (NPAIR + 1023) / 1024;  // 35
  int base = tid * C;
  int s = 0;
  for (int j = 0; j < C; ++j) {
    int idx = base + j;
    if (idx < NPAIR) s += cnt[idx];
  }
  part[tid] = s;
  __syncthreads();
  for (int off = 1; off < 1024; off <<= 1) {
    int v = 0;
    if (tid >= off) v = part[tid - off];
    __syncthreads();
    if (tid >= off) part[tid] += v;
    __syncthreads();
  }
  int run = tid ? part[tid - 1] : 0;
  for (int j = 0; j < C; ++j) {
    int idx = base + j;
    if (idx < NPAIR) { offs[idx] = run; run += cnt[idx]; }
  }
  if (tid == 1023) offs[NPAIR] = part[1023];
}
__global__ __launch_bounds__(256) void k_fill(const int* __restrict__ srcAll,
                                              const int* __restrict__ dstAll,
                                              const int* __restrict__ offs,
                                              int* __restrict__ cur,
                                              int* __restrict__ elist) {
  int i = blockIdx.x * 256 + threadIdx.x;  // 0..4*EG
  int rel = i >> 13;
  int id = rel * NN + dstAll[i];
  int pos = offs[id] + atomicAdd(&cur[id], 1);
  elist[pos] = srcAll[i];
}

// pre-aggregation: one wave per (rel,node): FB[node, (1+rel)*768 ..] =
// (1/deg) * sum over incoming edges of FB[src, 0:768]
__global__ __launch_bounds__(256) void k_preagg(ushort* __restrict__ FB,
                                                const int* __restrict__ offs,
                                                const int* __restrict__ elist,
                                                const float* __restrict__ rdeg) {
  int id = blockIdx.x * 4 + (threadIdx.x >> 6);
  if (id >= NPAIR) return;
  const int lane = threadIdx.x & 63;
  int rel = id / NN, node = id - rel * NN;
  int beg = offs[id], end = offs[id + 1];
  float acc[12] = {};
  for (int e = beg; e < end; ++e) {
    int src = elist[e];
    const ushort4* p = (const ushort4*)(FB + (size_t)src * KREL);
#pragma unroll
    for (int ps = 0; ps < 3; ++ps) {
      ushort4 u = p[ps * 64 + lane];
      acc[ps * 4 + 0] += bf2f(u.x);
      acc[ps * 4 + 1] += bf2f(u.y);
      acc[ps * 4 + 2] += bf2f(u.z);
      acc[ps * 4 + 3] += bf2f(u.w);
    }
  }
  float rd = rdeg[id];
  ushort4* q = (ushort4*)(FB + (size_t)node * KREL + (size_t)(1 + rel) * DD);
#pragma unroll
  for (int ps = 0; ps < 3; ++ps) {
    ushort4 o;
    o.x = f2bf(acc[ps * 4 + 0] * rd);
    o.y = f2bf(acc[ps * 4 + 1] * rd);
    o.z = f2bf(acc[ps * 4 + 2] * rd);
    o.w = f2bf(acc[ps * 4 + 3] * rd);
    q[ps * 64 + lane] = o;
  }
}

// ---------------------------------------------------------------------------
// bf16 MFMA GEMM body, generalized K (row stride of A and BT) and C stride.
__device__ __forceinline__ void mgemm_body(
    const ushort* __restrict__ A, const ushort* __restrict__ BT,
    const float* __restrict__ bias, const ushort* __restrict__ addCb,
    ushort* __restrict__ Cb, int M, int Kd, int Cstride, int relu,
    int bm, int bn, ushort* As, ushort* Bs) {
  const int tid = threadIdx.x;
  const int wave = tid >> 6, lane = tid & 63;
  const int lrow = lane & 15, quad = lane >> 4;

  const ushort* gA[4];
  const ushort* gB[4];
#pragma unroll
  for (int j = 0; j < 4; ++j) {
    int c = (wave * 4 + j) * 64 + lane;
    int row = c >> 3, kslot = c & 7;
    int kb = kslot ^ (row & 7);
    int ar = bm + row; ar = ar < M ? ar : M - 1;
    gA[j] = A + (size_t)ar * Kd + kb * 8;
    gB[j] = BT + (size_t)(bn + row) * Kd + kb * 8;
  }

  f32x4 acc[4][4];
#pragma unroll
  for (int i = 0; i < 4; ++i)
#pragma unroll
    for (int j = 0; j < 4; ++j) acc[i][j] = (f32x4){0.f, 0.f, 0.f, 0.f};

  const int wm = (wave >> 1) * 64, wn = (wave & 1) * 64;
  const int KT = Kd >> 6;

  for (int kt = 0; kt < KT; ++kt) {
#pragma unroll
    for (int j = 0; j < 4; ++j) {
      gload16(gA[j], &As[(wave * 4 + j) * 512]);
      gload16(gB[j], &Bs[(wave * 4 + j) * 512]);
      gA[j] += 64;
      gB[j] += 64;
    }
    __syncthreads();
#pragma unroll
    for (int ks = 0; ks < 2; ++ks) {
      bf16x8 af[4], bfr[4];
#pragma unroll
      for (int mi = 0; mi < 4; ++mi) {
        int r = wm + mi * 16 + lrow;
        int kc = ks * 4 + quad;
        af[mi] = *(const bf16x8*)&As[r * 64 + ((kc ^ (r & 7)) * 8)];
      }
#pragma unroll
      for (int ni = 0; ni < 4; ++ni) {
        int r = wn + ni * 16 + lrow;
        int kc = ks * 4 + quad;
        bfr[ni] = *(const bf16x8*)&Bs[r * 64 + ((kc ^ (r & 7)) * 8)];
      }
#pragma unroll
      for (int mi = 0; mi < 4; ++mi)
#pragma unroll
        for (int ni = 0; ni < 4; ++ni)
          acc[mi][ni] = __builtin_amdgcn_mfma_f32_16x16x32_bf16(
              af[mi], bfr[ni], acc[mi][ni], 0, 0, 0);
    }
    __syncthreads();
  }

#pragma unroll
  for (int mi = 0; mi < 4; ++mi) {
#pragma unroll
    for (int ni = 0; ni < 4; ++ni) {
      f32x4 v = acc[mi][ni];
      int col = bn + wn + ni * 16 + lrow;
      float bv = bias ? bias[col] : 0.f;
#pragma unroll
      for (int r = 0; r < 4; ++r) {
        int grow = bm + wm + mi * 16 + quad * 4 + r;
        if (grow >= M) continue;
        size_t off = (size_t)grow * Cstride + col;
        float t = v[r] + bv;
        if (addCb) t += bf2f(addCb[off]);
        if (relu) t = fmaxf(t, 0.f);
        Cb[off] = f2bf(t);
      }
    }
  }
}

__global__ __launch_bounds__(256) void k_mgemm(
    const ushort* __restrict__ A, const ushort* __restrict__ BT,
    const float* __restrict__ bias, const ushort* __restrict__ addCb,
    ushort* __restrict__ Cb, int M, int Kd, int Cstride, int relu) {
  __shared__ ushort As[8192], Bs[8192];
  mgemm_body(A, BT, bias, addCb, Cb, M, Kd, Cstride, relu,
             blockIdx.y * 128, blockIdx.x * 128, As, Bs);
}

// fused Q,K projection: grid (12, 256); x<6 -> Q, x>=6 -> K
__global__ __launch_bounds__(256) void k_mgemm_qk(
    const ushort* __restrict__ A, const ushort* __restrict__ BTq,
    const ushort* __restrict__ BTk, const float* __restrict__ bq,
    const float* __restrict__ bk, ushort* __restrict__ Qb,
    ushort* __restrict__ Kb) {
  __shared__ ushort As[8192], Bs[8192];
  int sel = blockIdx.x >= 6;
  mgemm_body(A, sel ? BTk : BTq, sel ? bk : bq, nullptr,
             sel ? Kb : Qb, MSW, DD, DD, 0,
             blockIdx.y * 128, (blockIdx.x - sel * 6) * 128, As, Bs);
}

// ---------------------------------------------------------------------------
// Attention (MFMA QK^T) + exact entmax-1.5 -> per-head-pair partials.
__global__ __launch_bounds__(256) void k_attn(const ushort* __restrict__ Q,
                                              const ushort* __restrict__ K,
                                              float* __restrict__ part) {
  __shared__ __align__(16) ushort qs[64 * 96];
  __shared__ __align__(16) ushort ks[64 * 96];
  const int s = blockIdx.x, hp = blockIdx.y;
  const int tid = threadIdx.x;
  const int wv = tid >> 6, lane = tid & 63;
  const int lrow = lane & 15, quad = lane >> 4;
  const int m0 = wv * 16;
  const float SC2 = 0.05103103630798288f;  // 0.5 / sqrt(96)

  float regacc[16];
#pragma unroll
  for (int i = 0; i < 16; ++i) regacc[i] = 0.f;

  for (int hh = 0; hh < 2; ++hh) {
    const int h = hp * 2 + hh;
    __syncthreads();
#pragma unroll
    for (int j = 0; j < 3; ++j) {
      int c = (j * 4 + wv) * 64 + lane;
      int row = c / 12, o = c % 12;
      const ushort* gq = Q + (size_t)(s * 64 + row) * DD + h * 96 + o * 8;
      const ushort* gk = K + (size_t)(s * 64 + row) * DD + h * 96 + o * 8;
      gload16(gq, &qs[(j * 4 + wv) * 512]);
      gload16(gk, &ks[(j * 4 + wv) * 512]);
    }
    __syncthreads();

    f32x4 acc4[4];
#pragma unroll
    for (int t = 0; t < 4; ++t) acc4[t] = (f32x4){0.f, 0.f, 0.f, 0.f};
#pragma unroll
    for (int k = 0; k < 3; ++k) {
      bf16x8 a = *(const bf16x8*)&qs[(m0 + lrow) * 96 + k * 32 + quad * 8];
#pragma unroll
      for (int t = 0; t < 4; ++t) {
        bf16x8 b = *(const bf16x8*)&ks[(t * 16 + lrow) * 96 + k * 32 + quad * 8];
        acc4[t] = __builtin_amdgcn_mfma_f32_16x16x32_bf16(a, b, acc4[t], 0, 0, 0);
      }
    }

#pragma unroll
    for (int r = 0; r < 16; ++r) {
      int srcl = (r >> 2) * 16 + lrow;
      float t0 = __shfl(acc4[0][r & 3], srcl, 64);
      float t1 = __shfl(acc4[1][r & 3], srcl, 64);
      float t2 = __shfl(acc4[2][r & 3], srcl, 64);
      float t3 = __shfl(acc4[3][r & 3], srcl, 64);
      float xv = quad == 0 ? t0 : quad == 1 ? t1 : quad == 2 ? t2 : t3;
      float x = xv * SC2;
      float z = x;
      for (int k = 2; k <= 64; k <<= 1)
        for (int j = k >> 1; j; j >>= 1) {
          float o = __shfl_xor(z, j, 64);
          bool lower = (lane & j) == 0;
          bool takeMax = ((lane & k) == 0) ? lower : !lower;
          z = takeMax ? fmaxf(z, o) : fminf(z, o);
        }
      float zmax = __shfl(z, 0, 64);
      z -= zmax;
      float xs = x - zmax;
      float cz = z, czz = z * z;
      for (int off = 1; off < 64; off <<= 1) {
        float t1s = __shfl_up(cz, off, 64);
        float t2s = __shfl_up(czz, off, 64);
        if (lane >= off) { cz += t1s; czz += t2s; }
      }
      float kk = (float)(lane + 1);
      float mean = cz / kk;
      float ssv = kk * (czz / kk - mean * mean);
      float delta = (1.f - ssv) / kk;
      float sq = delta > 0.f ? sqrtf(delta) : 0.f;
      float tau = mean - sq;
      unsigned long long bal = __ballot(tau <= z);
      int support = __popcll(bal);
      float tau_star = __shfl(tau, support - 1, 64);
      float p = fmaxf(xs - tau_star, 0.f);
      regacc[r] += p * p;
    }
  }
#pragma unroll
  for (int r = 0; r < 16; ++r)
    part[(size_t)hp * 2097152 + ((size_t)s * 64 + m0 + r) * 64 + lane] =
        regacc[r] * 0.125f;
}

// reduce 4 head-pair partials -> bf16 latent adjacency
__global__ __launch_bounds__(256) void k_latred(const float* __restrict__ part,
                                                ushort* __restrict__ latbf) {
  size_t i = (size_t)blockIdx.x * 256 + threadIdx.x;  // float4 units, 524288
  float4 a = ((const float4*)part)[i];
  float4 b = ((const float4*)(part + 2097152))[i];
  float4 c = ((const float4*)(part + 4194304))[i];
  float4 d = ((const float4*)(part + 6291456))[i];
  ushort4 o;
  o.x = f2bf(a.x + b.x + c.x + d.x);
  o.y = f2bf(a.y + b.y + c.y + d.y);
  o.z = f2bf(a.z + b.z + c.z + d.z);
  o.w = f2bf(a.w + b.w + c.w + d.w);
  ((ushort4*)latbf)[i] = o;
}

// ---------------------------------------------------------------------------
// Od[s]=dep[s]@Hh[s], Ol[s]=lat[s]@Hh[s]; 128-col tiles, grid (6, SS)
__global__ __launch_bounds__(256) void k_dualadj(const float* __restrict__ dep,
                                                 const ushort* __restrict__ lat,
                                                 const ushort* __restrict__ Hh,
                                                 ushort* __restrict__ Od,
                                                 ushort* __restrict__ Ol) {
  __shared__ float Pd[64][68];
  __shared__ ushort Pl[64][68];
  __shared__ float Hc[64][132];
  const int s = blockIdx.y;
  const int c0 = blockIdx.x * 128;
  const int tid = threadIdx.x;
  const int tx = tid & 15, ty = tid >> 4;
  for (int i = tid; i < 4096; i += 256)
    Pd[i >> 6][i & 63] = dep[(size_t)s * 4096 + i];
  for (int i = tid; i < 1024; i += 256) {
    int r = i >> 4, c = (i & 15) * 4;
    ushort4 u = ((const ushort4*)(lat + (size_t)s * 4096))[i];
    Pl[r][c + 0] = u.x; Pl[r][c + 1] = u.y;
    Pl[r][c + 2] = u.z; Pl[r][c + 3] = u.w;
  }
  for (int i = tid; i < 2048; i += 256) {
    int r = i >> 5, c = (i & 31) * 4;
    ushort4 u = *(const ushort4*)(Hh + (size_t)(s * 64 + r) * DD + c0 + c);
    float4 f;
    f.x = bf2f(u.x); f.y = bf2f(u.y); f.z = bf2f(u.z); f.w = bf2f(u.w);
    *(float4*)&Hc[r][c] = f;
  }
  __syncthreads();
  float ad[4][8] = {}, al[4][8] = {};
  for (int w2 = 0; w2 < 64; ++w2) {
    float4 b0 = *(const float4*)&Hc[w2][tx * 4];
    float4 b1 = *(const float4*)&Hc[w2][64 + tx * 4];
    float bb[8] = {b0.x, b0.y, b0.z, b0.w, b1.x, b1.y, b1.z, b1.w};
    float pd[4], pl[4];
#pragma unroll
    for (int i = 0; i < 4; ++i) {
      pd[i] = Pd[ty * 4 + i][w2];
      pl[i] = bf2f(Pl[ty * 4 + i][w2]);
    }
#pragma unroll
    for (int i = 0; i < 4; ++i)
#pragma unroll
      for (int j = 0; j < 8; ++j) {
        ad[i][j] = fmaf(pd[i], bb[j], ad[i][j]);
        al[i][j] = fmaf(pl[i], bb[j], al[i][j]);
      }
  }
#pragma unroll
  for (int i = 0; i < 4; ++i) {
    size_t ro = (size_t)(s * 64 + ty * 4 + i) * DD + c0;
    ushort4 v;
#pragma unroll
    for (int hh = 0; hh < 2; ++hh) {
      v.x = f2bf(ad[i][hh * 4 + 0]); v.y = f2bf(ad[i][hh * 4 + 1]);
      v.z = f2bf(ad[i][hh * 4 + 2]); v.w = f2bf(ad[i][hh * 4 + 3]);
      *(ushort4*)&Od[ro + hh * 64 + tx * 4] = v;
      v.x = f2bf(al[i][hh * 4 + 0]); v.y = f2bf(al[i][hh * 4 + 1]);
      v.z = f2bf(al[i][hh * 4 + 2]); v.w = f2bf(al[i][hh * 4 + 3]);
      *(ushort4*)&Ol[ro + hh * 64 + tx * 4] = v;
    }
  }
}

// gated fusion (+ optional fused residual add of word_embed)
__global__ __launch_bounds__(256) void k_gate(const ushort* __restrict__ g1,
                                              const ushort* __restrict__ om,
                                              const ushort* __restrict__ lm,
                                              const float* __restrict__ bias,
                                              const float* __restrict__ SE,
                                              const int* __restrict__ gidx,
                                              int fuse_res,
                                              ushort* __restrict__ dst) {
  size_t i = (size_t)blockIdx.x * 256 + threadIdx.x;  // 4-elem units
  ushort4 g4 = ((const ushort4*)g1)[i];
  ushort4 o4 = ((const ushort4*)om)[i];
  ushort4 l4 = ((const ushort4*)lm)[i];
  int col = (int)((i * 4) % DD);
  size_t row = i / 192;
  float4 res = make_float4(0.f, 0.f, 0.f, 0.f);
  if (fuse_res) res = ((const float4*)(SE + (size_t)gidx[row] * DD))[i % 192];
  float gv[4] = {bf2f(g4.x), bf2f(g4.y), bf2f(g4.z), bf2f(g4.w)};
  float ov[4] = {bf2f(o4.x), bf2f(o4.y), bf2f(o4.z), bf2f(o4.w)};
  float lv[4] = {bf2f(l4.x), bf2f(l4.y), bf2f(l4.z), bf2f(l4.w)};
  float rv[4] = {res.x, res.y, res.z, res.w};
  ushort4 r;
  ushort* rr = (ushort*)&r;
#pragma unroll
  for (int j = 0; j < 4; ++j) {
    float g = 1.f / (1.f + expf(-gv[j]));
    float v = g * ov[j] + (1.f - g) * lv[j] + bias[col + j];
    rr[j] = f2bf(fmaxf(v, 0.f) + rv[j]);
  }
  ((ushort4*)dst)[i] = r;
}

// node feature assembly -> bf16 FBIG[NN, KREL] (cols 0:768)
__global__ __launch_bounds__(256) void k_feats(const float* __restrict__ doc,
                                               const float* __restrict__ scls,
                                               const int* __restrict__ t_sid,
                                               const int* __restrict__ t_index,
                                               const ushort* __restrict__ X,
                                               ushort* __restrict__ F) {
  size_t i = (size_t)blockIdx.x * 256 + threadIdx.x;
  if (i >= (size_t)NN * 192) return;
  size_t n = i / 192, q = i % 192;
  ushort4 o;
  if (n <= SS) {
    float4 v = (n == 0) ? ((const float4*)doc)[q]
                        : ((const float4*)scls)[(n - 1) * 192 + q];
    o.x = f2bf(v.x); o.y = f2bf(v.y); o.z = f2bf(v.z); o.w = f2bf(v.w);
  } else {
    size_t t = n - 1 - SS;
    size_t row = (size_t)t_sid[t] * WW + t_index[t];
    o = ((const ushort4*)X)[row * 192 + q];
  }
  ((ushort4*)(F + n * KREL))[q] = o;
}

// final predictor; F/h1 strided (FBIG col 0), h2 contiguous
__global__ __launch_bounds__(256) void k_pred(const ushort* __restrict__ F,
                                              const ushort* __restrict__ h1,
                                              const ushort* __restrict__ h2,
                                              const float* __restrict__ pw,
                                              const float* __restrict__ pb,
                                              float* __restrict__ out) {
  const int n = blockIdx.x;
  const int tid = threadIdx.x;
  float acc[5] = {};
  for (int k = tid; k < 3 * DD; k += 256) {
    float v;
    if (k < DD) v = bf2f(F[(size_t)n * KREL + k]);
    else if (k < 2 * DD) v = bf2f(h1[(size_t)n * KREL + k - DD]);
    else v = bf2f(h2[(size_t)n * DD + k - 2 * DD]);
    const float* w = pw + (size_t)k * 5;
#pragma unroll
    for (int o = 0; o < 5; ++o) acc[o] = fmaf(v, w[o], acc[o]);
  }
#pragma unroll
  for (int o = 0; o < 5; ++o)
    for (int off = 32; off; off >>= 1) acc[o] += __shfl_xor(acc[o], off, 64);
  __shared__ float red[5][4];
  const int wv = tid >> 6, lane = tid & 63;
  if (lane == 0)
#pragma unroll
    for (int o = 0; o < 5; ++o) red[o][wv] = acc[o];
  __syncthreads();
  if (tid == 0)
#pragma unroll
    for (int o = 0; o < 5; ++o)
      out[(size_t)n * 5 + o] = red[o][0] + red[o][1] + red[o][2] + red[o][3] + pb[o];
}

// ---------------------------------------------------------------------------
extern "C" void kernel_launch(void* const* d_in, const int* in_sizes, int n_in,
                              void* d_out, int out_size, void* d_ws, size_t ws_size,
                              hipStream_t stream) {
  const float* sent_embed = (const float*)d_in[0];
  const float* s_idx      = (const float*)d_in[1];
  const float* dep_adj    = (const float*)d_in[2];
  const float* doc_cls    = (const float*)d_in[3];
  const float* sent_cls   = (const float*)d_in[4];
  const int*   t_sid      = (const int*)d_in[5];
  const int*   t_index    = (const int*)d_in[6];
  const int*   e_src      = (const int*)d_in[7];
  const int*   e_dst      = (const int*)d_in[8];
  const float* wq_b = (const float*)d_in[10];
  const float* wk_b = (const float*)d_in[12];
  const float* gc1_b   = (const float*)d_in[14];
  const float* gc1_l1b = (const float*)d_in[16];
  const float* gc1_l2b = (const float*)d_in[18];
  const float* gc2_b   = (const float*)d_in[20];
  const float* gc2_l1b = (const float*)d_in[22];
  const float* gc2_l2b = (const float*)d_in[24];
  const float* rel1_b = (const float*)d_in[27];
  const float* rel2_b = (const float*)d_in[30];
  const float* pred_w = (const float*)d_in[31];
  const float* pred_b = (const float*)d_in[32];
  float* out = (float*)d_out;

  // workspace carve (byte offsets), ~264 MiB total
  char* W = (char*)d_ws;
  ushort* A0 = (ushort*)W;                          // 64 MiB: WEbf -> FBIG2
  ushort* A1 = (ushort*)(W + (64ll << 20));         // 64 MiB: Q/Hh/G1 -> FBIG1
  ushort* A2 = (ushort*)(W + (128ll << 20));        // 48 MiB: K/Od
  ushort* A3 = (ushort*)(W + (176ll << 20));        // 48 MiB: PART/Ol
  ushort* LATbf = (ushort*)(W + (224ll << 20));     // 4 MiB
  ushort* WBF = (ushort*)(W + (228ll << 20));       // 9 MiB (8 matrices)
  ushort* WR  = (ushort*)(W + (238ll << 20));       // 11.25 MiB (2x768x3840)
  ushort* H2  = (ushort*)(W + (250ll << 20));       // 12.75 MiB
  char* M0 = W + (263ll << 20);
  int*   GIDX = (int*)M0;                           // 131072 B
  int*   DEGC = (int*)(M0 + 140000);
  float* RDEG = (float*)(M0 + 280000);
  int*   OFFS = (int*)(M0 + 420000);                // (NPAIR+1)*4
  int*   CUR  = (int*)(M0 + 560000);
  int*   ELIST= (int*)(M0 + 700000);                // 131072 B

  ushort* WEbf = A0;
  ushort* Qbf = A1, *Kbf = A2;
  float*  PART = (float*)A3;
  ushort* Hh = A1, *Od = A2, *Ol = A3, *G1 = A1;
  ushort* FBIG1 = A1;
  ushort* FBIG2 = A0;
  const size_t WRSZ = (size_t)DD * KREL;  // 2949120

  WTJobs wj;
  const char* nm[8];
  wj.j[0] = {(const float*)d_in[9],  WBF + 0 * (size_t)WSZ, DD};
  wj.j[1] = {(const float*)d_in[11], WBF + 1 * (size_t)WSZ, DD};
  wj.j[2] = {(const float*)d_in[13], WBF + 2 * (size_t)WSZ, DD};
  wj.j[3] = {(const float*)d_in[15], WBF + 3 * (size_t)WSZ, DD};
  wj.j[4] = {(const float*)d_in[17], WBF + 4 * (size_t)WSZ, DD};
  wj.j[5] = {(const float*)d_in[19], WBF + 5 * (size_t)WSZ, DD};
  wj.j[6] = {(const float*)d_in[21], WBF + 6 * (size_t)WSZ, DD};
  wj.j[7] = {(const float*)d_in[23], WBF + 7 * (size_t)WSZ, DD};
  wj.j[8] = {(const float*)d_in[26], WR + 0 * WRSZ, KREL};            // rel1 loop
  for (int r = 0; r < 4; ++r)
    wj.j[9 + r] = {(const float*)d_in[25] + (size_t)r * WSZ,
                   WR + 0 * WRSZ + (size_t)(1 + r) * DD, KREL};
  wj.j[13] = {(const float*)d_in[29], WR + 1 * WRSZ, KREL};           // rel2 loop
  for (int r = 0; r < 4; ++r)
    wj.j[14 + r] = {(const float*)d_in[28] + (size_t)r * WSZ,
                    WR + 1 * WRSZ + (size_t)(1 + r) * DD, KREL};

  dim3 blk(256);

  // 0) prep
  k_wtall<<<18 * 576, blk, 0, stream>>>(wj);
  k_pos<<<MSW / 4, blk, 0, stream>>>(s_idx, GIDX);
  k_gather<<<24576, blk, 0, stream>>>(sent_embed, GIDX, WEbf);
  hipMemsetAsync(DEGC, 0, NPAIR * 4, stream);
  hipMemsetAsync(CUR, 0, NPAIR * 4, stream);
  k_deg4<<<4 * EG / 256, blk, 0, stream>>>(e_dst, DEGC);
  k_rcp<<<(NPAIR + 255) / 256, blk, 0, stream>>>(DEGC, RDEG);
  k_scan<<<1, 1024, 0, stream>>>(DEGC, OFFS);
  k_fill<<<4 * EG / 256, blk, 0, stream>>>(e_src, e_dst, OFFS, CUR, ELIST);

  // 1) Q,K projections + attention + reduce
  k_mgemm_qk<<<dim3(12, 256), blk, 0, stream>>>(WEbf, WBF + 0 * (size_t)WSZ,
                                                WBF + 1 * (size_t)WSZ, wq_b, wk_b,
                                                Qbf, Kbf);
  k_attn<<<dim3(SS, 4), blk, 0, stream>>>(Qbf, Kbf, PART);
  k_latred<<<2048, blk, 0, stream>>>(PART, LATbf);

  // 2) gated GCN layers
  const int wIdx[2][3] = {{2, 3, 4}, {5, 6, 7}};
  const float* l1b[2] = {gc1_l1b, gc2_l1b};
  const float* l2b[2] = {gc1_l2b, gc2_l2b};
  const float* gb[2] = {gc1_b, gc2_b};
  for (int l = 0; l < 2; ++l) {
    k_mgemm<<<dim3(6, 256), blk, 0, stream>>>(WEbf,
        WBF + (size_t)wIdx[l][0] * WSZ, nullptr, nullptr, Hh, MSW, DD, DD, 0);
    k_dualadj<<<dim3(6, SS), blk, 0, stream>>>(dep_adj, LATbf, Hh, Od, Ol);
    k_mgemm<<<dim3(6, 256), blk, 0, stream>>>(Od,
        WBF + (size_t)wIdx[l][1] * WSZ, l1b[l], nullptr, G1, MSW, DD, DD, 0);
    k_mgemm<<<dim3(6, 256), blk, 0, stream>>>(Ol,
        WBF + (size_t)wIdx[l][2] * WSZ, l2b[l], G1, G1, MSW, DD, DD, 0);
    k_gate<<<24576, blk, 0, stream>>>(G1, Od, Ol, gb[l], sent_embed, GIDX,
                                      l == 1 ? 1 : 0, WEbf);
  }

  // 3) node features into FBIG1 col 0
  k_feats<<<6529, blk, 0, stream>>>(doc_cls, sent_cls, t_sid, t_index, WEbf, FBIG1);

  // 4) two relational GCN layers: CSR gather + one fused K=3840 GEMM each
  k_preagg<<<(NPAIR + 3) / 4, blk, 0, stream>>>(FBIG1, OFFS, ELIST, RDEG);
  k_mgemm<<<dim3(6, 69), blk, 0, stream>>>(FBIG1, WR + 0 * WRSZ, rel1_b, nullptr,
                                           FBIG2, NN, KREL, KREL, 1);
  k_preagg<<<(NPAIR + 3) / 4, blk, 0, stream>>>(FBIG2, OFFS, ELIST, RDEG);
  k_mgemm<<<dim3(6, 69), blk, 0, stream>>>(FBIG2, WR + 1 * WRSZ, rel2_b, nullptr,
                                           H2, NN, KREL, DD, 1);

  // 5) predictor
  k_pred<<<NN, blk, 0, stream>>>(FBIG1, FBIG2, H2, pred_w, pred_b, out);
}